// Round 6
// baseline (24446.034 us; speedup 1.0000x reference)
//
#include <hip/hip_runtime.h>

#define NPT 20000
#define DIMK 256
#define HD 128
#define KC 64
#define NT 17
#define NSLOT (KC*NT)          // 1088
#define SINK_IT 50
#define GB 256                 // coop grid blocks
#define BT 512                 // coop block threads
#define NWAVE (GB*(BT/64))     // 2048
#define RPW 10                 // rows per wave (2000 waves carry rows)
#define CHB ((NPT + GB - 1)/GB)  // 79 points per block in Lloyd

// ---- scratch offsets (floats) inside the T region of d_out ----
#define OFF_H     0
#define OFF_CL    (NPT*HD)                   // 2,560,000
#define OFF_Q     (OFF_CL + NPT*KC)          // 3,840,000
#define OFF_ORDER (OFF_Q + KC*NPT)           // 5,120,000 (ints)
#define OFF_TSV   (OFF_ORDER + NPT)
#define OFF_OFFS  (OFF_TSV + NPT)            // 32 ints
#define OFF_CENTS (OFF_OFFS + 32)            // 128 f
#define OFF_I0    (OFF_CENTS + 128)
#define OFF_SUB   (OFF_I0 + 32)
#define OFF_PM    (OFF_SUB + 128)            // NWAVE*2*64 f
#define OFF_PS    (OFF_PM + NWAVE*2*64)
#define OFF_PT    (OFF_PS + NWAVE*2*64)      // NWAVE*2 ints
#define OFF_PL    (OFF_PT + NWAVE*2)         // 2*GB f (lvl partials: m then s)
#define OFF_LVG   (OFF_PL + 2*GB)            // 1089 -> pad 1152
#define OFF_BP    (OFF_LVG + 1152)           // GB*192 (lloyd partials)
#define OFF_BAR   (OFF_BP + GB*192)          // 32 uints
// end ~= 5.74M floats << 21.76M floats of T region

__device__ __forceinline__ void tf2x32(unsigned k0, unsigned k1,
                                       unsigned x0, unsigned x1,
                                       unsigned& o0, unsigned& o1) {
  // JAX threefry2x32 block cipher (20 rounds, Random123 constants)
  unsigned ks0 = k0, ks1 = k1, ks2 = k0 ^ k1 ^ 0x1BD11BDAu;
  x0 += ks0; x1 += ks1;
  const int rot[2][4] = {{13,15,26,6},{17,29,16,24}};
  unsigned ks[3] = {ks0, ks1, ks2};
  #pragma unroll
  for (int i = 0; i < 5; ++i) {
    #pragma unroll
    for (int r = 0; r < 4; ++r) {
      int rr = rot[i & 1][r];
      x0 += x1;
      x1 = (x1 << rr) | (x1 >> (32 - rr));
      x1 ^= x0;
    }
    x0 += ks[(i+1)%3];
    x1 += ks[(i+2)%3] + (unsigned)(i+1);
  }
  o0 = x0; o1 = x1;
}

// running / pairwise logsumexp merge: (m,s) <- (m,s) + (m2,s2)
__device__ __forceinline__ void lse_merge(float& m, float& s, float m2, float s2) {
  float mn = fmaxf(m, m2);
  s = s*__expf(m - mn) + s2*__expf(m2 - mn);
  m = mn;
}

// ---------------- custom grid barrier (sense-reversal, agent scope) ----------------
__device__ __forceinline__ void gbar(unsigned* bar) {
  __syncthreads();
  if (threadIdx.x == 0) {
    unsigned e = __hip_atomic_load(&bar[16], __ATOMIC_RELAXED, __HIP_MEMORY_SCOPE_AGENT);
    unsigned old = __hip_atomic_fetch_add(&bar[0], 1u, __ATOMIC_ACQ_REL, __HIP_MEMORY_SCOPE_AGENT);
    if (old == (unsigned)(gridDim.x - 1)) {
      __hip_atomic_store(&bar[0], 0u, __ATOMIC_RELAXED, __HIP_MEMORY_SCOPE_AGENT);
      __hip_atomic_store(&bar[16], e + 1u, __ATOMIC_RELEASE, __HIP_MEMORY_SCOPE_AGENT);
    } else {
      while (__hip_atomic_load(&bar[16], __ATOMIC_ACQUIRE, __HIP_MEMORY_SCOPE_AGENT) == e)
        __builtin_amdgcn_s_sleep(4);
    }
  }
  __syncthreads();
}

__global__ void k_binit(unsigned* bar) {
  if (threadIdx.x < 32) bar[threadIdx.x] = 0u;
}

// ---------------- K1: key chain + randint i0 (verified in R5) ----------------
__global__ void k_keys(unsigned* sub, int* i0p) {
  if (threadIdx.x != 0 || blockIdx.x != 0) return;
  unsigned key0 = 0u, key1 = 42u;            // jax.random.key(42)
  unsigned c0, c1, s0, s1;
  tf2x32(key0, key1, 0u, 0u, c0, c1);
  tf2x32(key0, key1, 0u, 1u, s0, s1);
  key0 = c0; key1 = c1;
  // randint's internal split of k0:
  unsigned k1a, k1b, k2a, k2b;
  tf2x32(s0, s1, 0u, 0u, k1a, k1b);
  tf2x32(s0, s1, 0u, 1u, k2a, k2b);
  unsigned h0, h1, l0, l1;
  tf2x32(k1a, k1b, 0u, 0u, h0, h1);
  tf2x32(k2a, k2b, 0u, 0u, l0, l1);
  unsigned hb = h0 ^ h1, lb = l0 ^ l1;
  unsigned span = 20000u;
  unsigned m1 = 65536u % span;
  unsigned mult = (unsigned)(((unsigned long long)m1 * m1) % span);  // 7296
  unsigned off32 = (hb % span) * mult + (lb % span);
  *i0p = (int)(off32 % span);
  sub[0] = 0u; sub[1] = 0u;
  for (int i = 1; i < KC; ++i) {
    tf2x32(key0, key1, 0u, 0u, c0, c1);
    tf2x32(key0, key1, 0u, 1u, s0, s1);
    key0 = c0; key1 = c1;
    sub[2*i] = s0; sub[2*i+1] = s1;
  }
}

// ---------------- K2: Q[step][i] = exp(gumbel) = -1/log(u) (monotone form) ----------------
__global__ __launch_bounds__(256) void k_gumbel(const unsigned* __restrict__ sub,
                                                float* __restrict__ Q) {
  int s = blockIdx.y + 1;
  int i = blockIdx.x * 256 + threadIdx.x;
  if (i >= NPT) return;
  unsigned o0, o1;
  tf2x32(sub[2*s], sub[2*s+1], 0u, (unsigned)i, o0, o1);
  unsigned bits = o0 ^ o1;                    // partitionable 32-bit fold
  unsigned fb = (bits >> 9) | 0x3f800000u;
  float u = __uint_as_float(fb) - 1.0f;
  if (u == 0.0f) u = 1.17549435e-38f;         // minval = finfo.tiny
  Q[(size_t)s*NPT + i] = -1.0f / logf(u);     // exp(-log(-log u)) exactly
}

// ---------------- K3: h = selu(emb @ W1 + b1) ----------------
__global__ __launch_bounds__(256) void k_gemm(const float* __restrict__ emb,
                                              const float* __restrict__ W1,
                                              const float* __restrict__ b1,
                                              float* __restrict__ h) {
  __shared__ float As[64][64];   // [k][row]
  __shared__ float Bs[64][HD];   // [k][col]
  const int m0 = blockIdx.x * 64;
  const int tid = threadIdx.x;
  const int tx = tid & 31;
  const int ty = tid >> 5;
  float acc[8][4];
  #pragma unroll
  for (int a = 0; a < 8; ++a)
    #pragma unroll
    for (int c = 0; c < 4; ++c) acc[a][c] = 0.f;

  for (int kc = 0; kc < DIMK; kc += 64) {
    #pragma unroll
    for (int it = 0; it < 4; ++it) {
      int f = it*256 + tid;
      int r = f >> 4;
      int kk = (f & 15) << 2;
      float4 v = make_float4(0.f,0.f,0.f,0.f);
      if (m0 + r < NPT)
        v = *(const float4*)(emb + (size_t)(m0 + r)*DIMK + kc + kk);
      As[kk+0][r] = v.x; As[kk+1][r] = v.y; As[kk+2][r] = v.z; As[kk+3][r] = v.w;
    }
    #pragma unroll
    for (int it = 0; it < 8; ++it) {
      int f = it*256 + tid;
      int kk = f >> 5;
      int cc = (f & 31) << 2;
      *(float4*)&Bs[kk][cc] = *(const float4*)(W1 + (size_t)(kc + kk)*HD + cc);
    }
    __syncthreads();
    #pragma unroll 8
    for (int kk = 0; kk < 64; ++kk) {
      float4 a0 = *(float4*)&As[kk][ty*8];
      float4 a1 = *(float4*)&As[kk][ty*8+4];
      float4 bb = *(float4*)&Bs[kk][tx*4];
      float av[8] = {a0.x,a0.y,a0.z,a0.w,a1.x,a1.y,a1.z,a1.w};
      float bv[4] = {bb.x,bb.y,bb.z,bb.w};
      #pragma unroll
      for (int a = 0; a < 8; ++a)
        #pragma unroll
        for (int c = 0; c < 4; ++c) acc[a][c] += av[a]*bv[c];
    }
    __syncthreads();
  }
  const float SC = 1.0507009873554805f, AL = 1.6732632423543772f;
  #pragma unroll
  for (int a = 0; a < 8; ++a) {
    int r = m0 + ty*8 + a;
    if (r >= NPT) continue;
    float4 o;
    float* po = &o.x;
    #pragma unroll
    for (int c = 0; c < 4; ++c) {
      float x = acc[a][c] + b1[tx*4 + c];
      float v = (x > 0.f) ? x : AL * expm1f(x);
      po[c] = SC * v;
    }
    *(float4*)(h + (size_t)r*HD + tx*4) = o;
  }
}

// ---------------- K4: c_learned = sqdist(h, protos[:64]) ----------------
__global__ __launch_bounds__(256) void k_cl(const float* __restrict__ h,
                                            const float* __restrict__ protos,
                                            float* __restrict__ cl) {
  __shared__ float ps[KC][129];
  __shared__ float hs[4][HD];
  const int tid = threadIdx.x;
  #pragma unroll
  for (int it = 0; it < 32; ++it) {
    int f = it*256 + tid;
    ps[f >> 7][f & 127] = protos[f];
  }
  const int i0r = blockIdx.x * 4;
  for (int f = tid; f < 4*HD; f += 256) {
    int rr = f >> 7, d = f & 127;
    int gi = i0r + rr;
    hs[rr][d] = (gi < NPT) ? h[(size_t)gi*HD + d] : 0.f;
  }
  __syncthreads();
  const int j = tid & 63, rq = tid >> 6;
  const int gi = i0r + rq;
  if (gi < NPT) {
    float dot = 0.f, hh = 0.f, pp = 0.f;
    #pragma unroll 8
    for (int d = 0; d < HD; ++d) {
      float a = hs[rq][d], b = ps[j][d];
      dot += a*b; hh += a*a; pp += b*b;
    }
    float c = hh + pp - 2.f*dot;
    cl[(size_t)gi*KC + j] = fmaxf(c, 0.f);
  }
}

// ---------------- K5: sort + kmeans++ (single block, no grid syncs) ----------------
__global__ __launch_bounds__(512) void k_sortkm(const float* __restrict__ pos,
                                                const int* __restrict__ jt,
                                                const int* __restrict__ i0p,
                                                const float* __restrict__ Q,
                                                int* order, int* tsv, int* offs,
                                                float* centsg) {
  __shared__ union {
    struct { unsigned cnt[512][NT]; int tot[NT]; int base[NT]; } srt;
    struct { float red[8]; int redi[8]; float S; int bsel; } km;
  } sm;
  const int tid = threadIdx.x;
  const int lane = tid & 63, wv = tid >> 6;

  // ===== stable counting sort by joint type =====
  {
    const int CHS = 40;
    const int r0 = tid*CHS, r1 = min(NPT, r0 + CHS);
    for (int t = 0; t < NT; ++t) sm.srt.cnt[tid][t] = 0;
    __syncthreads();
    for (int r = r0; r < r1; ++r) sm.srt.cnt[tid][jt[r]]++;
    __syncthreads();
    if (tid < NT) {
      unsigned s = 0;
      for (int i = 0; i < 512; ++i) s += sm.srt.cnt[i][tid];
      sm.srt.tot[tid] = (int)s;
    }
    __syncthreads();
    if (tid == 0) {
      int acc = 0;
      for (int t = 0; t < NT; ++t) { sm.srt.base[t] = acc; offs[t] = acc; acc += sm.srt.tot[t]; }
      offs[NT] = acc;
    }
    __syncthreads();
    if (tid < NT) {
      unsigned run = (unsigned)sm.srt.base[tid];
      for (int i = 0; i < 512; ++i) { unsigned c = sm.srt.cnt[i][tid]; sm.srt.cnt[i][tid] = run; run += c; }
    }
    __syncthreads();
    for (int r = r0; r < r1; ++r) {
      int t = jt[r];
      unsigned p = sm.srt.cnt[tid][t]++;
      order[p] = r; tsv[p] = t;
    }
    __syncthreads();
  }

  // ===== kmeans++ (points resident in registers) =====
  float px[40], py[40], dm[40];
  const int i0 = *i0p;
  const float c0x = pos[2*i0], c0y = pos[2*i0+1];
  if (tid == 0) { centsg[0] = c0x; centsg[1] = c0y; }
  #pragma unroll
  for (int u = 0; u < 40; ++u) {
    int i = tid + u*512;
    bool v = i < NPT;
    float x = v ? pos[2*i]   : 0.f;
    float y = v ? pos[2*i+1] : 0.f;
    px[u] = x; py[u] = y;
    float d = (x*x + y*y) + (c0x*c0x + c0y*c0y) - 2.f*(x*c0x + y*c0y);
    dm[u] = v ? fmaxf(d, 0.f) : 0.f;
  }
  __syncthreads();
  for (int s = 1; s < KC; ++s) {
    float loc = 0.f;
    #pragma unroll
    for (int u = 0; u < 40; ++u) loc += dm[u];
    for (int o = 32; o; o >>= 1) loc += __shfl_xor(loc, o, 64);
    if (lane == 0) sm.km.red[wv] = loc;
    __syncthreads();
    if (tid == 0) {
      float S = 0.f;
      for (int w = 0; w < 8; ++w) S += sm.km.red[w];
      sm.km.S = S;
    }
    __syncthreads();
    const float invS = 1.0f/(sm.km.S + 1e-8f);
    float bsc = -3.4e38f; int bi = 0x7FFFFFFF;
    const float* Qs = Q + (size_t)s*NPT;
    #pragma unroll
    for (int u = 0; u < 40; ++u) {
      int i = tid + u*512;
      if (i < NPT) {
        // monotone transform of argmax( log(p+1e-12) + gumbel ): (p+1e-12)*exp(g)
        float sc = (dm[u]*invS + 1e-12f) * Qs[i];
        if (sc > bsc || (sc == bsc && i < bi)) { bsc = sc; bi = i; }
      }
    }
    for (int o = 32; o; o >>= 1) {
      float osc = __shfl_xor(bsc, o, 64);
      int   oid = __shfl_xor(bi, o, 64);
      if (osc > bsc || (osc == bsc && oid < bi)) { bsc = osc; bi = oid; }
    }
    __syncthreads();
    if (lane == 0) { sm.km.red[wv] = bsc; sm.km.redi[wv] = bi; }
    __syncthreads();
    if (tid == 0) {
      float bb = -3.4e38f; int bj = 0x7FFFFFFF;
      for (int w = 0; w < 8; ++w) {
        float v2 = sm.km.red[w]; int id2 = sm.km.redi[w];
        if (v2 > bb || (v2 == bb && id2 < bj)) { bb = v2; bj = id2; }
      }
      sm.km.bsel = bj;
    }
    __syncthreads();
    const int sel = sm.km.bsel;
    const float cx = pos[2*sel], cy = pos[2*sel+1];
    if (tid == 0) { centsg[2*s] = cx; centsg[2*s+1] = cy; }
    #pragma unroll
    for (int u = 0; u < 40; ++u) {
      float x = px[u], y = py[u];
      float d = (x*x + y*y) + (cx*cx + cy*cy) - 2.f*(x*cx + y*cy);
      dm[u] = fminf(dm[u], fmaxf(d, 0.f));
    }
    __syncthreads();
  }
}

// ---------------- distributed log_v build (slots spread over grid) ----------------
__device__ __forceinline__ void build_lv(int b, int tid, const int* offs,
                                         const float* PM, const float* PS, const int* PT,
                                         const float* PLm, const float* PLs,
                                         float* lvg, float LOGTGT) {
  int g = b*BT + tid;
  if (g < NSLOT) {
    int t = g >> 6, j = g & 63;
    int wa = offs[t] / RPW;
    int wb = (offs[t+1] - 1) / RPW;
    float m = -3.4e38f, s = 0.f;
    for (int ww = wa; ww <= wb; ++ww) {
      if (PT[ww*2+0] == t) lse_merge(m, s, PM[(ww*2+0)*64 + j], PS[(ww*2+0)*64 + j]);
      if (PT[ww*2+1] == t) lse_merge(m, s, PM[(ww*2+1)*64 + j], PS[(ww*2+1)*64 + j]);
    }
    lvg[g] = -(__logf(s) + m);
  } else if (g == NSLOT) {
    float m = -3.4e38f, s = 0.f;
    for (int bb = 0; bb < GB; ++bb) lse_merge(m, s, PLm[bb], PLs[bb]);
    lvg[NSLOT] = LOGTGT - (__logf(s) + m);
  }
}

// ---------------- K6: cooperative kernel — Lloyd + cost + Sinkhorn + V ----------------
__global__ __launch_bounds__(BT) void k_main(const float* __restrict__ pos,
                                             float* TS, float* vals) {
  const int tid = threadIdx.x, b = blockIdx.x;
  const int lane = tid & 63, wv = tid >> 6;
  const int w = b*(BT/64) + wv;          // global wave id

  float* cl     = TS + OFF_CL;
  int*   order  = (int*)(TS + OFF_ORDER);
  int*   tsv    = (int*)(TS + OFF_TSV);
  int*   offs   = (int*)(TS + OFF_OFFS);
  float* centsg = TS + OFF_CENTS;
  float* PM     = TS + OFF_PM;
  float* PS     = TS + OFF_PS;
  int*   PT     = (int*)(TS + OFF_PT);
  float* PLm    = TS + OFF_PL;
  float* PLs    = TS + OFF_PL + GB;
  float* lvg    = TS + OFF_LVG;
  float* bp     = TS + OFF_BP;
  unsigned* bar = (unsigned*)(TS + OFF_BAR);

  __shared__ float lv[NSLOT];
  __shared__ float lvl_sh;
  __shared__ float cents[KC][2];
  __shared__ int   asg[CHB];
  __shared__ float comb[192];
  __shared__ float plm[BT/64], pls[BT/64];

  // ===== Lloyd: 10 iterations (2 barriers each) =====
  const int pbase = b*CHB;
  const int pcnt  = max(0, min(NPT - pbase, CHB));
  for (int it = 0; it < 10; ++it) {
    if (tid < KC) { cents[tid][0] = centsg[2*tid]; cents[tid][1] = centsg[2*tid+1]; }
    __syncthreads();
    if (tid < pcnt) {
      int i = pbase + tid;
      float x = pos[2*i], y = pos[2*i+1];
      float bd = 3.4e38f; int bj = 0;
      #pragma unroll 4
      for (int j = 0; j < KC; ++j) {
        float cx = cents[j][0], cy = cents[j][1];
        float d = (x*x + y*y) + (cx*cx + cy*cy) - 2.f*(x*cx + y*cy);
        d = fmaxf(d, 0.f);
        if (d < bd) { bd = d; bj = j; }
      }
      asg[tid] = bj;
    }
    __syncthreads();
    if (wv == 0) {
      float sx = 0.f, sy = 0.f, cn = 0.f;
      for (int r = 0; r < pcnt; ++r) {
        int a = asg[r]; int i = pbase + r;
        float x = pos[2*i], y = pos[2*i+1];
        if (lane == a) { sx += x; sy += y; cn += 1.f; }
      }
      bp[b*192 + lane]       = sx;
      bp[b*192 + 64 + lane]  = sy;
      bp[b*192 + 128 + lane] = cn;
    }
    gbar(bar);
    if (b == 0) {
      if (tid < 192) {
        int f = tid >> 6, l = tid & 63;
        float s = 0.f;
        for (int bb = 0; bb < GB; ++bb) s += bp[bb*192 + f*64 + l];
        comb[tid] = s;
      }
      __syncthreads();
      if (tid < KC) {
        float cn = comb[128 + tid];
        if (cn > 0.f) {
          float dv = fmaxf(cn, 1.f);
          centsg[2*tid]   = comb[tid] / dv;
          centsg[2*tid+1] = comb[64 + tid] / dv;
        }
      }
    }
    gbar(bar);
  }

  // ===== CB: build this wave's 10 rows of -cost/TAU into registers =====
  if (tid < KC) { cents[tid][0] = centsg[2*tid]; cents[tid][1] = centsg[2*tid+1]; }
  __syncthreads();
  const int r0 = w*RPW;
  const int nr = max(0, min(NPT - r0, RPW));
  float Lsr[RPW], lgu[RPW];
  int typu[RPW], ordu[RPW];
  #pragma unroll
  for (int u = 0; u < RPW; ++u) {
    Lsr[u] = 0.f; lgu[u] = 0.f; typu[u] = 0; ordu[u] = 0;
    if (u < nr) {
      int ii = r0 + u;
      int od = order[ii], t = tsv[ii];
      ordu[u] = od; typu[u] = t;
      float x = pos[2*od], y = pos[2*od+1];
      float cx = cents[lane][0], cy = cents[lane][1];
      float cs = (x*x + y*y) + (cx*cx + cy*cy) - 2.f*(x*cx + y*cy);
      cs = fmaxf(cs, 0.f);
      float cle = cl[(size_t)od*KC + lane];
      Lsr[u] = -(cs + 0.5f*cle) / 0.05f;
    }
  }

  // ===== Sinkhorn: 50 iterations, register-resident rows =====
  const float LOGTGT = logf((float)(NPT - NSLOT));   // log(18912)
  for (int it = 1; it <= SINK_IT; ++it) {
    if (it > 1) {
      build_lv(b, tid, offs, PM, PS, PT, PLm, PLs, lvg, LOGTGT);
      gbar(bar);
    }
    for (int s2 = tid; s2 < NSLOT; s2 += BT) lv[s2] = (it == 1) ? 0.f : lvg[s2];
    if (tid == 0) lvl_sh = (it == 1) ? 0.f : lvg[NSLOT];
    __syncthreads();
    const float lvls = lvl_sh;

    float amA = -3.4e38f, asA = 0.f, amB = -3.4e38f, asB = 0.f;
    int rtA = (nr > 0) ? typu[0] : -1, rtB = -1;
    float lm = -3.4e38f, lssum = 0.f;
    #pragma unroll
    for (int u = 0; u < RPW; ++u) {
      if (u < nr) {
        float x = Lsr[u] + lv[typu[u]*KC + lane];
        float m = x;
        for (int o = 32; o; o >>= 1) m = fmaxf(m, __shfl_xor(m, o, 64));
        m = fmaxf(m, lvls);
        float e = __expf(x - m);
        for (int o = 32; o; o >>= 1) e += __shfl_xor(e, o, 64);
        e += __expf(lvls - m);
        float lu = -(__logf(e) + m);
        lgu[u] = lu;
        float cv = Lsr[u] + lu;                 // L + log_u (column contribution)
        if (typu[u] == rtA) { lse_merge(amA, asA, cv, 1.0f); }
        else { if (rtB < 0) rtB = typu[u]; lse_merge(amB, asB, cv, 1.0f); }
        lse_merge(lm, lssum, lu, 1.0f);         // dummy-column partial
      }
    }
    if (nr > 0) {
      PM[(w*2+0)*64 + lane] = amA; PS[(w*2+0)*64 + lane] = asA;
      PM[(w*2+1)*64 + lane] = amB; PS[(w*2+1)*64 + lane] = asB;
      if (lane == 0) { PT[w*2] = rtA; PT[w*2+1] = rtB; }
    }
    if (lane == 0) { plm[wv] = lm; pls[wv] = lssum; }
    __syncthreads();
    if (tid == 0) {
      float m2 = -3.4e38f, s2v = 0.f;
      for (int q = 0; q < BT/64; ++q) lse_merge(m2, s2v, plm[q], pls[q]);
      PLm[b] = m2; PLs[b] = s2v;
    }
    gbar(bar);
  }

  // ===== final log_v + V: write active transport values =====
  build_lv(b, tid, offs, PM, PS, PT, PLm, PLs, lvg, LOGTGT);
  gbar(bar);
  for (int s2 = tid; s2 < NSLOT; s2 += BT) lv[s2] = lvg[s2];
  __syncthreads();
  #pragma unroll
  for (int u = 0; u < RPW; ++u) {
    if (u < nr)
      vals[(size_t)ordu[u]*KC + lane] = __expf(Lsr[u] + lv[typu[u]*KC + lane] + lgu[u]);
  }
}

// ---------------- K7: expand vals into full T (zeros elsewhere) ----------------
__global__ __launch_bounds__(256) void k_T(const float* __restrict__ vals,
                                           const int* __restrict__ jt,
                                           float* __restrict__ T) {
  __shared__ float v[KC];
  const int i = blockIdx.x;
  const int tid = threadIdx.x;
  if (tid < KC) v[tid] = vals[(size_t)i*KC + tid];
  __syncthreads();
  const int t = jt[i];
  for (int e = tid; e < NSLOT; e += 256) {
    int j = e / NT;
    int tt = e - j*NT;
    T[(size_t)i*NSLOT + e] = (tt == t) ? v[j] : 0.0f;
  }
}

// ---------------- K8: logits = log(vals + 1e-8) in place ----------------
__global__ __launch_bounds__(256) void k_logits(float* logits) {
  int idx = blockIdx.x*256 + threadIdx.x;
  if (idx < NPT*KC) logits[idx] = logf(logits[idx] + 1e-8f);
}

extern "C" void kernel_launch(void* const* d_in, const int* in_sizes, int n_in,
                              void* d_out, int out_size, void* d_ws, size_t ws_size,
                              hipStream_t stream) {
  const float* emb    = (const float*)d_in[0];
  const float* pos    = (const float*)d_in[1];
  const float* W1     = (const float*)d_in[2];
  const float* b1     = (const float*)d_in[3];
  const float* protos = (const float*)d_in[4];
  const int*   jt     = (const int*)d_in[5];
  // d_in[6] = k (device scalar) — fixed at 64 by setup_inputs.

  float* out  = (float*)d_out;
  float* vals = out;                        // logits region (written last)
  float* T    = out + (size_t)NPT*KC;       // T region doubles as scratch
  float* TS   = T;

  unsigned* sub = (unsigned*)(TS + OFF_SUB);
  int* i0p = (int*)(TS + OFF_I0);

  hipLaunchKernelGGL(k_keys, dim3(1), dim3(64), 0, stream, sub, i0p);
  hipLaunchKernelGGL(k_gumbel, dim3((NPT + 255)/256, KC - 1), dim3(256), 0, stream,
                     sub, TS + OFF_Q);
  hipLaunchKernelGGL(k_gemm, dim3((NPT + 63)/64), dim3(256), 0, stream,
                     emb, W1, b1, TS + OFF_H);
  hipLaunchKernelGGL(k_cl, dim3((NPT + 3)/4), dim3(256), 0, stream,
                     TS + OFF_H, protos, TS + OFF_CL);
  hipLaunchKernelGGL(k_sortkm, dim3(1), dim3(512), 0, stream,
                     pos, jt, i0p, TS + OFF_Q,
                     (int*)(TS + OFF_ORDER), (int*)(TS + OFF_TSV),
                     (int*)(TS + OFF_OFFS), TS + OFF_CENTS);
  hipLaunchKernelGGL(k_binit, dim3(1), dim3(64), 0, stream,
                     (unsigned*)(TS + OFF_BAR));

  const float* pos_a = pos; float* TS_a = TS; float* vals_a = vals;
  void* kargs[] = { (void*)&pos_a, (void*)&TS_a, (void*)&vals_a };
  hipLaunchCooperativeKernel((const void*)k_main, dim3(GB), dim3(BT), kargs, 0, stream);

  hipLaunchKernelGGL(k_T, dim3(NPT), dim3(256), 0, stream, vals, jt, T);
  hipLaunchKernelGGL(k_logits, dim3((NPT*KC + 255)/256), dim3(256), 0, stream, vals);
}

// Round 7
// 2146.526 us; speedup vs baseline: 11.3887x; 11.3887x over previous
//
#include <hip/hip_runtime.h>

#define NPT 20000
#define DIMK 256
#define HD 128
#define KC 64
#define NT 17
#define NSLOT (KC*NT)          // 1088
#define SINK_IT 50
#define NBLK 250               // sinkhorn/cb blocks: 80 rows each
#define RPB 80
#define LGB 64                 // lloyd blocks
#define CPB 313                // lloyd points per block (64*313 >= 20000)

// ---- scratch offsets (floats) inside the T region of d_out ----
#define OFF_H     0
#define OFF_CL    (NPT*HD)                   // 2,560,000
#define OFF_Q     (OFF_CL + NPT*KC)
#define OFF_LS    (OFF_Q + KC*NPT)
#define OFF_LOGU  (OFF_LS + NPT*KC)
#define OFF_ORDER (OFF_LOGU + NPT)
#define OFF_TSV   (OFF_ORDER + NPT)
#define OFF_OFFS  (OFF_TSV + NPT)            // 32 ints
#define OFF_CENTS (OFF_OFFS + 32)            // 128 f
#define OFF_I0    (OFF_CENTS + 128)
#define OFF_SUB   (OFF_I0 + 32)
#define OFF_LLP   (OFF_SUB + 128)            // LGB*192
#define OFF_PMB   (OFF_LLP + LGB*192)        // NBLK*3*64 = 48000
#define OFF_PSB   (OFF_PMB + NBLK*3*64)
#define OFF_RUNT  (OFF_PSB + NBLK*3*64)      // 750 ints -> 768
#define OFF_PLM   (OFF_RUNT + 768)           // 256
#define OFF_PLS   (OFF_PLM + 256)            // 256
// end ~= 6.53M floats << 21.76M floats of T region

__device__ __forceinline__ void tf2x32(unsigned k0, unsigned k1,
                                       unsigned x0, unsigned x1,
                                       unsigned& o0, unsigned& o1) {
  unsigned ks0 = k0, ks1 = k1, ks2 = k0 ^ k1 ^ 0x1BD11BDAu;
  x0 += ks0; x1 += ks1;
  const int rot[2][4] = {{13,15,26,6},{17,29,16,24}};
  unsigned ks[3] = {ks0, ks1, ks2};
  #pragma unroll
  for (int i = 0; i < 5; ++i) {
    #pragma unroll
    for (int r = 0; r < 4; ++r) {
      int rr = rot[i & 1][r];
      x0 += x1;
      x1 = (x1 << rr) | (x1 >> (32 - rr));
      x1 ^= x0;
    }
    x0 += ks[(i+1)%3];
    x1 += ks[(i+2)%3] + (unsigned)(i+1);
  }
  o0 = x0; o1 = x1;
}

__device__ __forceinline__ void lse_merge(float& m, float& s, float m2, float s2) {
  float mn = fmaxf(m, m2);
  s = s*__expf(m - mn) + s2*__expf(m2 - mn);
  m = mn;
}

// ---------------- K1: key chain + randint i0 (verified R5) ----------------
__global__ void k_keys(unsigned* sub, int* i0p) {
  if (threadIdx.x != 0 || blockIdx.x != 0) return;
  unsigned key0 = 0u, key1 = 42u;
  unsigned c0, c1, s0, s1;
  tf2x32(key0, key1, 0u, 0u, c0, c1);
  tf2x32(key0, key1, 0u, 1u, s0, s1);
  key0 = c0; key1 = c1;
  unsigned k1a, k1b, k2a, k2b;
  tf2x32(s0, s1, 0u, 0u, k1a, k1b);
  tf2x32(s0, s1, 0u, 1u, k2a, k2b);
  unsigned h0, h1, l0, l1;
  tf2x32(k1a, k1b, 0u, 0u, h0, h1);
  tf2x32(k2a, k2b, 0u, 0u, l0, l1);
  unsigned hb = h0 ^ h1, lb = l0 ^ l1;
  unsigned span = 20000u;
  unsigned m1 = 65536u % span;
  unsigned mult = (unsigned)(((unsigned long long)m1 * m1) % span);  // 7296
  unsigned off32 = (hb % span) * mult + (lb % span);
  *i0p = (int)(off32 % span);
  sub[0] = 0u; sub[1] = 0u;
  for (int i = 1; i < KC; ++i) {
    tf2x32(key0, key1, 0u, 0u, c0, c1);
    tf2x32(key0, key1, 0u, 1u, s0, s1);
    key0 = c0; key1 = c1;
    sub[2*i] = s0; sub[2*i+1] = s1;
  }
}

// ---------------- K2: Q[step][i] = exp(gumbel) = -1/log(u) ----------------
__global__ __launch_bounds__(256) void k_gumbel(const unsigned* __restrict__ sub,
                                                float* __restrict__ Q) {
  int s = blockIdx.y + 1;
  int i = blockIdx.x * 256 + threadIdx.x;
  if (i >= NPT) return;
  unsigned o0, o1;
  tf2x32(sub[2*s], sub[2*s+1], 0u, (unsigned)i, o0, o1);
  unsigned bits = o0 ^ o1;
  unsigned fb = (bits >> 9) | 0x3f800000u;
  float u = __uint_as_float(fb) - 1.0f;
  if (u == 0.0f) u = 1.17549435e-38f;
  Q[(size_t)s*NPT + i] = -1.0f / logf(u);
}

// ---------------- K3: h = selu(emb @ W1 + b1) ----------------
__global__ __launch_bounds__(256) void k_gemm(const float* __restrict__ emb,
                                              const float* __restrict__ W1,
                                              const float* __restrict__ b1,
                                              float* __restrict__ h) {
  __shared__ float As[64][64];
  __shared__ float Bs[64][HD];
  const int m0 = blockIdx.x * 64;
  const int tid = threadIdx.x;
  const int tx = tid & 31;
  const int ty = tid >> 5;
  float acc[8][4];
  #pragma unroll
  for (int a = 0; a < 8; ++a)
    #pragma unroll
    for (int c = 0; c < 4; ++c) acc[a][c] = 0.f;

  for (int kc = 0; kc < DIMK; kc += 64) {
    #pragma unroll
    for (int it = 0; it < 4; ++it) {
      int f = it*256 + tid;
      int r = f >> 4;
      int kk = (f & 15) << 2;
      float4 v = make_float4(0.f,0.f,0.f,0.f);
      if (m0 + r < NPT)
        v = *(const float4*)(emb + (size_t)(m0 + r)*DIMK + kc + kk);
      As[kk+0][r] = v.x; As[kk+1][r] = v.y; As[kk+2][r] = v.z; As[kk+3][r] = v.w;
    }
    #pragma unroll
    for (int it = 0; it < 8; ++it) {
      int f = it*256 + tid;
      int kk = f >> 5;
      int cc = (f & 31) << 2;
      *(float4*)&Bs[kk][cc] = *(const float4*)(W1 + (size_t)(kc + kk)*HD + cc);
    }
    __syncthreads();
    #pragma unroll 8
    for (int kk = 0; kk < 64; ++kk) {
      float4 a0 = *(float4*)&As[kk][ty*8];
      float4 a1 = *(float4*)&As[kk][ty*8+4];
      float4 bb = *(float4*)&Bs[kk][tx*4];
      float av[8] = {a0.x,a0.y,a0.z,a0.w,a1.x,a1.y,a1.z,a1.w};
      float bv[4] = {bb.x,bb.y,bb.z,bb.w};
      #pragma unroll
      for (int a = 0; a < 8; ++a)
        #pragma unroll
        for (int c = 0; c < 4; ++c) acc[a][c] += av[a]*bv[c];
    }
    __syncthreads();
  }
  const float SC = 1.0507009873554805f, AL = 1.6732632423543772f;
  #pragma unroll
  for (int a = 0; a < 8; ++a) {
    int r = m0 + ty*8 + a;
    if (r >= NPT) continue;
    float4 o;
    float* po = &o.x;
    #pragma unroll
    for (int c = 0; c < 4; ++c) {
      float x = acc[a][c] + b1[tx*4 + c];
      float v = (x > 0.f) ? x : AL * expm1f(x);
      po[c] = SC * v;
    }
    *(float4*)(h + (size_t)r*HD + tx*4) = o;
  }
}

// ---------------- K4: c_learned = sqdist(h, protos[:64]) ----------------
__global__ __launch_bounds__(256) void k_cl(const float* __restrict__ h,
                                            const float* __restrict__ protos,
                                            float* __restrict__ cl) {
  __shared__ float ps[KC][129];
  __shared__ float hs[4][HD];
  const int tid = threadIdx.x;
  #pragma unroll
  for (int it = 0; it < 32; ++it) {
    int f = it*256 + tid;
    ps[f >> 7][f & 127] = protos[f];
  }
  const int i0r = blockIdx.x * 4;
  for (int f = tid; f < 4*HD; f += 256) {
    int rr = f >> 7, d = f & 127;
    int gi = i0r + rr;
    hs[rr][d] = (gi < NPT) ? h[(size_t)gi*HD + d] : 0.f;
  }
  __syncthreads();
  const int j = tid & 63, rq = tid >> 6;
  const int gi = i0r + rq;
  if (gi < NPT) {
    float dot = 0.f, hh = 0.f, pp = 0.f;
    #pragma unroll 8
    for (int d = 0; d < HD; ++d) {
      float a = hs[rq][d], b = ps[j][d];
      dot += a*b; hh += a*a; pp += b*b;
    }
    float c = hh + pp - 2.f*dot;
    cl[(size_t)gi*KC + j] = fmaxf(c, 0.f);
  }
}

// ---------------- K5: sort + kmeans++ (single block) ----------------
__global__ __launch_bounds__(512) void k_sortkm(const float* __restrict__ pos,
                                                const int* __restrict__ jt,
                                                const int* __restrict__ i0p,
                                                const float* __restrict__ Q,
                                                int* order, int* tsv, int* offs,
                                                float* centsg) {
  __shared__ union {
    struct { unsigned cnt[512][NT]; int tot[NT]; int base[NT]; } srt;
    struct { float red[8]; int redi[8]; float S; int bsel; } km;
  } sm;
  const int tid = threadIdx.x;
  const int lane = tid & 63, wv = tid >> 6;
  {
    const int CHS = 40;
    const int r0 = tid*CHS, r1 = min(NPT, r0 + CHS);
    for (int t = 0; t < NT; ++t) sm.srt.cnt[tid][t] = 0;
    __syncthreads();
    for (int r = r0; r < r1; ++r) sm.srt.cnt[tid][jt[r]]++;
    __syncthreads();
    if (tid < NT) {
      unsigned s = 0;
      for (int i = 0; i < 512; ++i) s += sm.srt.cnt[i][tid];
      sm.srt.tot[tid] = (int)s;
    }
    __syncthreads();
    if (tid == 0) {
      int acc = 0;
      for (int t = 0; t < NT; ++t) { sm.srt.base[t] = acc; offs[t] = acc; acc += sm.srt.tot[t]; }
      offs[NT] = acc;
    }
    __syncthreads();
    if (tid < NT) {
      unsigned run = (unsigned)sm.srt.base[tid];
      for (int i = 0; i < 512; ++i) { unsigned c = sm.srt.cnt[i][tid]; sm.srt.cnt[i][tid] = run; run += c; }
    }
    __syncthreads();
    for (int r = r0; r < r1; ++r) {
      int t = jt[r];
      unsigned p = sm.srt.cnt[tid][t]++;
      order[p] = r; tsv[p] = t;
    }
    __syncthreads();
  }
  float px[40], py[40], dm[40];
  const int i0 = *i0p;
  const float c0x = pos[2*i0], c0y = pos[2*i0+1];
  if (tid == 0) { centsg[0] = c0x; centsg[1] = c0y; }
  #pragma unroll
  for (int u = 0; u < 40; ++u) {
    int i = tid + u*512;
    bool v = i < NPT;
    float x = v ? pos[2*i]   : 0.f;
    float y = v ? pos[2*i+1] : 0.f;
    px[u] = x; py[u] = y;
    float d = (x*x + y*y) + (c0x*c0x + c0y*c0y) - 2.f*(x*c0x + y*c0y);
    dm[u] = v ? fmaxf(d, 0.f) : 0.f;
  }
  __syncthreads();
  for (int s = 1; s < KC; ++s) {
    float loc = 0.f;
    #pragma unroll
    for (int u = 0; u < 40; ++u) loc += dm[u];
    for (int o = 32; o; o >>= 1) loc += __shfl_xor(loc, o, 64);
    if (lane == 0) sm.km.red[wv] = loc;
    __syncthreads();
    if (tid == 0) {
      float S = 0.f;
      for (int w = 0; w < 8; ++w) S += sm.km.red[w];
      sm.km.S = S;
    }
    __syncthreads();
    const float invS = 1.0f/(sm.km.S + 1e-8f);
    float bsc = -3.4e38f; int bi = 0x7FFFFFFF;
    const float* Qs = Q + (size_t)s*NPT;
    #pragma unroll
    for (int u = 0; u < 40; ++u) {
      int i = tid + u*512;
      if (i < NPT) {
        float sc = (dm[u]*invS + 1e-12f) * Qs[i];
        if (sc > bsc || (sc == bsc && i < bi)) { bsc = sc; bi = i; }
      }
    }
    for (int o = 32; o; o >>= 1) {
      float osc = __shfl_xor(bsc, o, 64);
      int   oid = __shfl_xor(bi, o, 64);
      if (osc > bsc || (osc == bsc && oid < bi)) { bsc = osc; bi = oid; }
    }
    __syncthreads();
    if (lane == 0) { sm.km.red[wv] = bsc; sm.km.redi[wv] = bi; }
    __syncthreads();
    if (tid == 0) {
      float bb = -3.4e38f; int bj = 0x7FFFFFFF;
      for (int w = 0; w < 8; ++w) {
        float v2 = sm.km.red[w]; int id2 = sm.km.redi[w];
        if (v2 > bb || (v2 == bb && id2 < bj)) { bb = v2; bj = id2; }
      }
      sm.km.bsel = bj;
    }
    __syncthreads();
    const int sel = sm.km.bsel;
    const float cx = pos[2*sel], cy = pos[2*sel+1];
    if (tid == 0) { centsg[2*s] = cx; centsg[2*s+1] = cy; }
    #pragma unroll
    for (int u = 0; u < 40; ++u) {
      float x = px[u], y = py[u];
      float d = (x*x + y*y) + (cx*cx + cy*cy) - 2.f*(x*cx + y*cy);
      dm[u] = fminf(dm[u], fmaxf(d, 0.f));
    }
    __syncthreads();
  }
}

// ---------------- K6: one Lloyd iteration (grid LGB=64) ----------------
// first==0: combine prev partials redundantly -> new cents (block 0 writes back)
__global__ __launch_bounds__(512) void k_lloyd(const float* __restrict__ pos,
                                               float* centsg, float* llp, int first) {
  const int b = blockIdx.x, tid = threadIdx.x, lane = tid & 63, wv = tid >> 6;
  __shared__ float cents[KC][2];
  __shared__ float comb[192];
  __shared__ float wpart[8][192];
  __shared__ int asg[CPB];
  if (tid < KC) { cents[tid][0] = centsg[2*tid]; cents[tid][1] = centsg[2*tid+1]; }
  __syncthreads();
  if (!first) {
    if (tid < 192) {
      float s = 0.f;
      for (int bb = 0; bb < LGB; ++bb) s += llp[bb*192 + tid];
      comb[tid] = s;
    }
    __syncthreads();
    if (tid < KC) {
      float cn = comb[128 + tid];
      if (cn > 0.f) {
        float dv = fmaxf(cn, 1.f);
        cents[tid][0] = comb[tid] / dv;
        cents[tid][1] = comb[64 + tid] / dv;
      }
    }
    __syncthreads();
    if (b == 0 && tid < KC) {   // benign same-value race (all blocks compute identical cents)
      centsg[2*tid] = cents[tid][0]; centsg[2*tid+1] = cents[tid][1];
    }
  }
  const int base = b*CPB;
  const int pcnt = max(0, min(NPT - base, CPB));
  if (tid < pcnt) {
    int i = base + tid;
    float x = pos[2*i], y = pos[2*i+1];
    float bd = 3.4e38f; int bj = 0;
    #pragma unroll 4
    for (int j = 0; j < KC; ++j) {
      float cx = cents[j][0], cy = cents[j][1];
      float d = (x*x + y*y) + (cx*cx + cy*cy) - 2.f*(x*cx + y*cy);
      d = fmaxf(d, 0.f);
      if (d < bd) { bd = d; bj = j; }
    }
    asg[tid] = bj;
  }
  __syncthreads();
  {
    int r0 = 40*wv, r1 = min(pcnt, r0 + 40);
    float sx = 0.f, sy = 0.f, cn = 0.f;
    for (int r = r0; r < r1; ++r) {
      int a = asg[r]; int i = base + r;
      float x = pos[2*i], y = pos[2*i+1];
      if (lane == a) { sx += x; sy += y; cn += 1.f; }
    }
    wpart[wv][lane] = sx; wpart[wv][64+lane] = sy; wpart[wv][128+lane] = cn;
  }
  __syncthreads();
  if (tid < 192) {
    float s = 0.f;
    #pragma unroll
    for (int w8 = 0; w8 < 8; ++w8) s += wpart[w8][tid];
    llp[b*192 + tid] = s;
  }
}

// ---------------- K7: final cent combine + cost build + run table (grid NBLK) ----------------
__global__ __launch_bounds__(512) void k_cb(const float* __restrict__ pos,
                                            const float* __restrict__ cl,
                                            const int* __restrict__ order,
                                            const int* __restrict__ tsv,
                                            const float* __restrict__ centsg,
                                            const float* __restrict__ llp,
                                            float* __restrict__ Ls, int* runT) {
  const int b = blockIdx.x, tid = threadIdx.x, lane = tid & 63, wv = tid >> 6;
  __shared__ float cents[KC][2];
  __shared__ float comb[192];
  if (tid < KC) { cents[tid][0] = centsg[2*tid]; cents[tid][1] = centsg[2*tid+1]; }
  __syncthreads();
  if (tid < 192) {
    float s = 0.f;
    for (int bb = 0; bb < LGB; ++bb) s += llp[bb*192 + tid];
    comb[tid] = s;
  }
  __syncthreads();
  if (tid < KC) {
    float cn = comb[128 + tid];
    if (cn > 0.f) {
      float dv = fmaxf(cn, 1.f);
      cents[tid][0] = comb[tid] / dv;
      cents[tid][1] = comb[64 + tid] / dv;
    }
  }
  if (tid == 0) {
    int nrun = 0, prev = -1;
    int rt[3] = {-1,-1,-1};
    for (int u = 0; u < RPB; ++u) {
      int t = tsv[b*RPB + u];
      if (t != prev) { if (nrun < 3) rt[nrun] = t; nrun++; prev = t; }
    }
    runT[b*3+0] = rt[0]; runT[b*3+1] = rt[1]; runT[b*3+2] = rt[2];
  }
  __syncthreads();
  #pragma unroll
  for (int k = 0; k < 10; ++k) {
    int ii = b*RPB + wv*10 + k;
    int od = order[ii];
    float x = pos[2*od], y = pos[2*od+1];
    float cx = cents[lane][0], cy = cents[lane][1];
    float cs = fmaxf((x*x + y*y) + (cx*cx + cy*cy) - 2.f*(x*cx + y*cy), 0.f);
    float cle = cl[(size_t)od*KC + lane];
    Ls[(size_t)ii*KC + lane] = -(cs + 0.5f*cle) / 0.05f;
  }
}

// ---------------- K8: one Sinkhorn iteration (grid NBLK) ----------------
template<int FIRST>
__global__ __launch_bounds__(512) void k_sink(const float* __restrict__ Ls,
                                              float* __restrict__ logu,
                                              const int* __restrict__ offs,
                                              const int* __restrict__ runT,
                                              const int* __restrict__ tsv,
                                              float* __restrict__ PMb, float* __restrict__ PSb,
                                              float* __restrict__ PLm, float* __restrict__ PLs) {
  const int b = blockIdx.x, tid = threadIdx.x, lane = tid & 63, wv = tid >> 6;
  __shared__ float lvs[3][64];
  __shared__ float wpm[8][2][64], wps[8][2][64];
  __shared__ int   wri[8][2];
  __shared__ float plmw[8], plsw[8];
  __shared__ float lvl_sh;
  const int rt0 = runT[b*3+0], rt1 = runT[b*3+1], rt2 = runT[b*3+2];

  if (!FIRST) {
    if (wv < 3) {
      int t = (wv == 0) ? rt0 : ((wv == 1) ? rt1 : rt2);
      if (t >= 0) {
        float m = -3.4e38f, s = 0.f;
        int bb0 = offs[t] / RPB, bb1 = (offs[t+1] - 1) / RPB;
        for (int bb = bb0; bb <= bb1; ++bb) {
          #pragma unroll
          for (int q = 0; q < 3; ++q) {
            if (runT[bb*3+q] == t)
              lse_merge(m, s, PMb[(bb*3+q)*64 + lane], PSb[(bb*3+q)*64 + lane]);
          }
        }
        lvs[wv][lane] = -(__logf(s) + m);
      }
    } else if (wv == 3) {
      float m = -3.4e38f, s = 0.f;
      for (int bb = lane; bb < NBLK; bb += 64) lse_merge(m, s, PLm[bb], PLs[bb]);
      for (int o = 32; o; o >>= 1) {
        float m2 = __shfl_xor(m, o, 64), s2 = __shfl_xor(s, o, 64);
        lse_merge(m, s, m2, s2);
      }
      if (lane == 0) lvl_sh = logf((float)(NPT - NSLOT)) - (__logf(s) + m);
    }
    __syncthreads();
  }
  const float lvl = FIRST ? 0.f : lvl_sh;

  float am0 = -3.4e38f, as0 = 0.f, am1 = -3.4e38f, as1 = 0.f;
  int r0i = -1, r1i = -1;
  float lm = -3.4e38f, lss = 0.f;
  #pragma unroll
  for (int k = 0; k < 10; ++k) {
    int ii = b*RPB + wv*10 + k;
    int t = tsv[ii];
    int rq = (t == rt0) ? 0 : ((t == rt1) ? 1 : 2);
    float lvv = FIRST ? 0.f : lvs[rq][lane];
    float Lv = Ls[(size_t)ii*KC + lane];
    float x = Lv + lvv;
    float m = x;
    for (int o = 32; o; o >>= 1) m = fmaxf(m, __shfl_xor(m, o, 64));
    m = fmaxf(m, lvl);
    float e = __expf(x - m);
    for (int o = 32; o; o >>= 1) e += __shfl_xor(e, o, 64);
    e += __expf(lvl - m);
    float lu = -(__logf(e) + m);
    if (lane == 0) logu[ii] = lu;
    float cv = Lv + lu;
    if (r0i < 0 || rq == r0i) { r0i = rq; lse_merge(am0, as0, cv, 1.0f); }
    else                      { r1i = rq; lse_merge(am1, as1, cv, 1.0f); }
    lse_merge(lm, lss, lu, 1.0f);
  }
  wpm[wv][0][lane] = am0; wps[wv][0][lane] = as0;
  wpm[wv][1][lane] = am1; wps[wv][1][lane] = as1;
  if (lane == 0) { wri[wv][0] = r0i; wri[wv][1] = r1i; plmw[wv] = lm; plsw[wv] = lss; }
  __syncthreads();
  if (wv < 3) {
    float m = -3.4e38f, s = 0.f;
    for (int w8 = 0; w8 < 8; ++w8) {
      if (wri[w8][0] == wv) lse_merge(m, s, wpm[w8][0][lane], wps[w8][0][lane]);
      if (wri[w8][1] == wv) lse_merge(m, s, wpm[w8][1][lane], wps[w8][1][lane]);
    }
    PMb[(b*3+wv)*64 + lane] = m; PSb[(b*3+wv)*64 + lane] = s;
  } else if (wv == 3 && lane == 0) {
    float m = -3.4e38f, s = 0.f;
    #pragma unroll
    for (int w8 = 0; w8 < 8; ++w8) lse_merge(m, s, plmw[w8], plsw[w8]);
    PLm[b] = m; PLs[b] = s;
  }
}

// ---------------- K9: final log_v + vals ----------------
__global__ __launch_bounds__(512) void k_fin(const float* __restrict__ Ls,
                                             const float* __restrict__ logu,
                                             const int* __restrict__ offs,
                                             const int* __restrict__ runT,
                                             const int* __restrict__ tsv,
                                             const int* __restrict__ order,
                                             const float* __restrict__ PMb,
                                             const float* __restrict__ PSb,
                                             float* __restrict__ vals) {
  const int b = blockIdx.x, tid = threadIdx.x, lane = tid & 63, wv = tid >> 6;
  __shared__ float lvs[3][64];
  const int rt0 = runT[b*3+0], rt1 = runT[b*3+1], rt2 = runT[b*3+2];
  if (wv < 3) {
    int t = (wv == 0) ? rt0 : ((wv == 1) ? rt1 : rt2);
    if (t >= 0) {
      float m = -3.4e38f, s = 0.f;
      int bb0 = offs[t] / RPB, bb1 = (offs[t+1] - 1) / RPB;
      for (int bb = bb0; bb <= bb1; ++bb) {
        #pragma unroll
        for (int q = 0; q < 3; ++q) {
          if (runT[bb*3+q] == t)
            lse_merge(m, s, PMb[(bb*3+q)*64 + lane], PSb[(bb*3+q)*64 + lane]);
        }
      }
      lvs[wv][lane] = -(__logf(s) + m);
    }
  }
  __syncthreads();
  #pragma unroll
  for (int k = 0; k < 10; ++k) {
    int ii = b*RPB + wv*10 + k;
    int t = tsv[ii];
    int rq = (t == rt0) ? 0 : ((t == rt1) ? 1 : 2);
    vals[(size_t)order[ii]*KC + lane] =
        __expf(Ls[(size_t)ii*KC + lane] + lvs[rq][lane] + logu[ii]);
  }
}

// ---------------- K10: expand vals into full T ----------------
__global__ __launch_bounds__(256) void k_T(const float* __restrict__ vals,
                                           const int* __restrict__ jt,
                                           float* __restrict__ T) {
  __shared__ float v[KC];
  const int i = blockIdx.x;
  const int tid = threadIdx.x;
  if (tid < KC) v[tid] = vals[(size_t)i*KC + tid];
  __syncthreads();
  const int t = jt[i];
  for (int e = tid; e < NSLOT; e += 256) {
    int j = e / NT;
    int tt = e - j*NT;
    T[(size_t)i*NSLOT + e] = (tt == t) ? v[j] : 0.0f;
  }
}

// ---------------- K11: logits = log(vals + 1e-8) ----------------
__global__ __launch_bounds__(256) void k_logits(float* logits) {
  int idx = blockIdx.x*256 + threadIdx.x;
  if (idx < NPT*KC) logits[idx] = logf(logits[idx] + 1e-8f);
}

extern "C" void kernel_launch(void* const* d_in, const int* in_sizes, int n_in,
                              void* d_out, int out_size, void* d_ws, size_t ws_size,
                              hipStream_t stream) {
  const float* emb    = (const float*)d_in[0];
  const float* pos    = (const float*)d_in[1];
  const float* W1     = (const float*)d_in[2];
  const float* b1     = (const float*)d_in[3];
  const float* protos = (const float*)d_in[4];
  const int*   jt     = (const int*)d_in[5];

  float* out  = (float*)d_out;
  float* vals = out;
  float* T    = out + (size_t)NPT*KC;
  float* TS   = T;

  unsigned* sub = (unsigned*)(TS + OFF_SUB);
  int* i0p    = (int*)(TS + OFF_I0);
  int* order  = (int*)(TS + OFF_ORDER);
  int* tsv    = (int*)(TS + OFF_TSV);
  int* offs   = (int*)(TS + OFF_OFFS);
  int* runT   = (int*)(TS + OFF_RUNT);
  float* centsg = TS + OFF_CENTS;
  float* llp  = TS + OFF_LLP;
  float* Ls   = TS + OFF_LS;
  float* logu = TS + OFF_LOGU;
  float* PMb  = TS + OFF_PMB;
  float* PSb  = TS + OFF_PSB;
  float* PLm  = TS + OFF_PLM;
  float* PLs  = TS + OFF_PLS;

  hipLaunchKernelGGL(k_keys, dim3(1), dim3(64), 0, stream, sub, i0p);
  hipLaunchKernelGGL(k_gumbel, dim3((NPT + 255)/256, KC - 1), dim3(256), 0, stream,
                     sub, TS + OFF_Q);
  hipLaunchKernelGGL(k_gemm, dim3((NPT + 63)/64), dim3(256), 0, stream,
                     emb, W1, b1, TS + OFF_H);
  hipLaunchKernelGGL(k_cl, dim3((NPT + 3)/4), dim3(256), 0, stream,
                     TS + OFF_H, protos, TS + OFF_CL);
  hipLaunchKernelGGL(k_sortkm, dim3(1), dim3(512), 0, stream,
                     pos, jt, i0p, TS + OFF_Q, order, tsv, offs, centsg);

  for (int it = 0; it < 10; ++it)
    hipLaunchKernelGGL(k_lloyd, dim3(LGB), dim3(512), 0, stream,
                       pos, centsg, llp, (it == 0) ? 1 : 0);

  hipLaunchKernelGGL(k_cb, dim3(NBLK), dim3(512), 0, stream,
                     pos, TS + OFF_CL, order, tsv, centsg, llp, Ls, runT);

  hipLaunchKernelGGL(k_sink<1>, dim3(NBLK), dim3(512), 0, stream,
                     Ls, logu, offs, runT, tsv, PMb, PSb, PLm, PLs);
  for (int it = 1; it < SINK_IT; ++it)
    hipLaunchKernelGGL(k_sink<0>, dim3(NBLK), dim3(512), 0, stream,
                       Ls, logu, offs, runT, tsv, PMb, PSb, PLm, PLs);

  hipLaunchKernelGGL(k_fin, dim3(NBLK), dim3(512), 0, stream,
                     Ls, logu, offs, runT, tsv, order, PMb, PSb, vals);

  hipLaunchKernelGGL(k_T, dim3(NPT), dim3(256), 0, stream, vals, jt, T);
  hipLaunchKernelGGL(k_logits, dim3((NPT*KC + 255)/256), dim3(256), 0, stream, vals);
}

// Round 8
// 1867.815 us; speedup vs baseline: 13.0880x; 1.1492x over previous
//
#include <hip/hip_runtime.h>

#define NPT 20000
#define DIMK 256
#define HD 128
#define KC 64
#define NT 17
#define NSLOT (KC*NT)          // 1088
#define SINK_IT 50
#define NBLK 250               // sinkhorn/cb blocks: 80 rows each
#define RPB 80
#define LGB 64                 // lloyd blocks
#define CPB 313                // lloyd points per block (64*313 >= 20000)

// ---- scratch offsets (floats) inside the T region of d_out ----
#define OFF_H     0
#define OFF_CL    (NPT*HD)                   // 2,560,000
#define OFF_Q     (OFF_CL + NPT*KC)
#define OFF_LS    (OFF_Q + KC*NPT)
#define OFF_LOGU  (OFF_LS + NPT*KC)
#define OFF_ORDER (OFF_LOGU + NPT)
#define OFF_TSV   (OFF_ORDER + NPT)
#define OFF_OFFS  (OFF_TSV + NPT)            // 32 ints
#define OFF_CENTS (OFF_OFFS + 32)            // 128 f
#define OFF_I0    (OFF_CENTS + 128)
#define OFF_SUB   (OFF_I0 + 32)
#define OFF_LLP   (OFF_SUB + 128)            // LGB*192
#define OFF_PMB   (OFF_LLP + LGB*192)        // NBLK*3*64 = 48000
#define OFF_PSB   (OFF_PMB + NBLK*3*64)
#define OFF_RUNT  (OFF_PSB + NBLK*3*64)      // 750 ints -> 768
#define OFF_PLM   (OFF_RUNT + 768)           // 256
#define OFF_PLS   (OFF_PLM + 256)            // 256
// end ~= 6.53M floats << 21.76M floats of T region

__device__ __forceinline__ void tf2x32(unsigned k0, unsigned k1,
                                       unsigned x0, unsigned x1,
                                       unsigned& o0, unsigned& o1) {
  unsigned ks0 = k0, ks1 = k1, ks2 = k0 ^ k1 ^ 0x1BD11BDAu;
  x0 += ks0; x1 += ks1;
  const int rot[2][4] = {{13,15,26,6},{17,29,16,24}};
  unsigned ks[3] = {ks0, ks1, ks2};
  #pragma unroll
  for (int i = 0; i < 5; ++i) {
    #pragma unroll
    for (int r = 0; r < 4; ++r) {
      int rr = rot[i & 1][r];
      x0 += x1;
      x1 = (x1 << rr) | (x1 >> (32 - rr));
      x1 ^= x0;
    }
    x0 += ks[(i+1)%3];
    x1 += ks[(i+2)%3] + (unsigned)(i+1);
  }
  o0 = x0; o1 = x1;
}

__device__ __forceinline__ void lse_merge(float& m, float& s, float m2, float s2) {
  float mn = fmaxf(m, m2);
  s = s*__expf(m - mn) + s2*__expf(m2 - mn);
  m = mn;
}

// ---------------- K1: key chain + randint i0 (verified R5) ----------------
__global__ void k_keys(unsigned* sub, int* i0p) {
  if (threadIdx.x != 0 || blockIdx.x != 0) return;
  unsigned key0 = 0u, key1 = 42u;
  unsigned c0, c1, s0, s1;
  tf2x32(key0, key1, 0u, 0u, c0, c1);
  tf2x32(key0, key1, 0u, 1u, s0, s1);
  key0 = c0; key1 = c1;
  unsigned k1a, k1b, k2a, k2b;
  tf2x32(s0, s1, 0u, 0u, k1a, k1b);
  tf2x32(s0, s1, 0u, 1u, k2a, k2b);
  unsigned h0, h1, l0, l1;
  tf2x32(k1a, k1b, 0u, 0u, h0, h1);
  tf2x32(k2a, k2b, 0u, 0u, l0, l1);
  unsigned hb = h0 ^ h1, lb = l0 ^ l1;
  unsigned span = 20000u;
  unsigned m1 = 65536u % span;
  unsigned mult = (unsigned)(((unsigned long long)m1 * m1) % span);  // 7296
  unsigned off32 = (hb % span) * mult + (lb % span);
  *i0p = (int)(off32 % span);
  sub[0] = 0u; sub[1] = 0u;
  for (int i = 1; i < KC; ++i) {
    tf2x32(key0, key1, 0u, 0u, c0, c1);
    tf2x32(key0, key1, 0u, 1u, s0, s1);
    key0 = c0; key1 = c1;
    sub[2*i] = s0; sub[2*i+1] = s1;
  }
}

// ---------------- K2: Q[step][i] = exp(gumbel) = -1/log(u) ----------------
__global__ __launch_bounds__(256) void k_gumbel(const unsigned* __restrict__ sub,
                                                float* __restrict__ Q) {
  int s = blockIdx.y + 1;
  int i = blockIdx.x * 256 + threadIdx.x;
  if (i >= NPT) return;
  unsigned o0, o1;
  tf2x32(sub[2*s], sub[2*s+1], 0u, (unsigned)i, o0, o1);
  unsigned bits = o0 ^ o1;
  unsigned fb = (bits >> 9) | 0x3f800000u;
  float u = __uint_as_float(fb) - 1.0f;
  if (u == 0.0f) u = 1.17549435e-38f;
  Q[(size_t)s*NPT + i] = -1.0f / logf(u);
}

// ---------------- K3: h = selu(emb @ W1 + b1) ----------------
__global__ __launch_bounds__(256) void k_gemm(const float* __restrict__ emb,
                                              const float* __restrict__ W1,
                                              const float* __restrict__ b1,
                                              float* __restrict__ h) {
  __shared__ float As[64][64];
  __shared__ float Bs[64][HD];
  const int m0 = blockIdx.x * 64;
  const int tid = threadIdx.x;
  const int tx = tid & 31;
  const int ty = tid >> 5;
  float acc[8][4];
  #pragma unroll
  for (int a = 0; a < 8; ++a)
    #pragma unroll
    for (int c = 0; c < 4; ++c) acc[a][c] = 0.f;

  for (int kc = 0; kc < DIMK; kc += 64) {
    #pragma unroll
    for (int it = 0; it < 4; ++it) {
      int f = it*256 + tid;
      int r = f >> 4;
      int kk = (f & 15) << 2;
      float4 v = make_float4(0.f,0.f,0.f,0.f);
      if (m0 + r < NPT)
        v = *(const float4*)(emb + (size_t)(m0 + r)*DIMK + kc + kk);
      As[kk+0][r] = v.x; As[kk+1][r] = v.y; As[kk+2][r] = v.z; As[kk+3][r] = v.w;
    }
    #pragma unroll
    for (int it = 0; it < 8; ++it) {
      int f = it*256 + tid;
      int kk = f >> 5;
      int cc = (f & 31) << 2;
      *(float4*)&Bs[kk][cc] = *(const float4*)(W1 + (size_t)(kc + kk)*HD + cc);
    }
    __syncthreads();
    #pragma unroll 8
    for (int kk = 0; kk < 64; ++kk) {
      float4 a0 = *(float4*)&As[kk][ty*8];
      float4 a1 = *(float4*)&As[kk][ty*8+4];
      float4 bb = *(float4*)&Bs[kk][tx*4];
      float av[8] = {a0.x,a0.y,a0.z,a0.w,a1.x,a1.y,a1.z,a1.w};
      float bv[4] = {bb.x,bb.y,bb.z,bb.w};
      #pragma unroll
      for (int a = 0; a < 8; ++a)
        #pragma unroll
        for (int c = 0; c < 4; ++c) acc[a][c] += av[a]*bv[c];
    }
    __syncthreads();
  }
  const float SC = 1.0507009873554805f, AL = 1.6732632423543772f;
  #pragma unroll
  for (int a = 0; a < 8; ++a) {
    int r = m0 + ty*8 + a;
    if (r >= NPT) continue;
    float4 o;
    float* po = &o.x;
    #pragma unroll
    for (int c = 0; c < 4; ++c) {
      float x = acc[a][c] + b1[tx*4 + c];
      float v = (x > 0.f) ? x : AL * expm1f(x);
      po[c] = SC * v;
    }
    *(float4*)(h + (size_t)r*HD + tx*4) = o;
  }
}

// ---------------- K4: c_learned = sqdist(h, protos[:64]) ----------------
__global__ __launch_bounds__(256) void k_cl(const float* __restrict__ h,
                                            const float* __restrict__ protos,
                                            float* __restrict__ cl) {
  __shared__ float ps[KC][129];
  __shared__ float hs[4][HD];
  const int tid = threadIdx.x;
  #pragma unroll
  for (int it = 0; it < 32; ++it) {
    int f = it*256 + tid;
    ps[f >> 7][f & 127] = protos[f];
  }
  const int i0r = blockIdx.x * 4;
  for (int f = tid; f < 4*HD; f += 256) {
    int rr = f >> 7, d = f & 127;
    int gi = i0r + rr;
    hs[rr][d] = (gi < NPT) ? h[(size_t)gi*HD + d] : 0.f;
  }
  __syncthreads();
  const int j = tid & 63, rq = tid >> 6;
  const int gi = i0r + rq;
  if (gi < NPT) {
    float dot = 0.f, hh = 0.f, pp = 0.f;
    #pragma unroll 8
    for (int d = 0; d < HD; ++d) {
      float a = hs[rq][d], b = ps[j][d];
      dot += a*b; hh += a*a; pp += b*b;
    }
    float c = hh + pp - 2.f*dot;
    cl[(size_t)gi*KC + j] = fmaxf(c, 0.f);
  }
}

// ---------------- K5a: stable counting sort by joint type (single block) ----------------
__global__ __launch_bounds__(512) void k_sort(const int* __restrict__ jt,
                                              int* order, int* tsv, int* offs) {
  __shared__ struct { unsigned cnt[512][NT]; int tot[NT]; int base[NT]; } sm;
  const int tid = threadIdx.x;
  const int CHS = 40;
  const int r0 = tid*CHS, r1 = min(NPT, r0 + CHS);
  for (int t = 0; t < NT; ++t) sm.cnt[tid][t] = 0;
  __syncthreads();
  for (int r = r0; r < r1; ++r) sm.cnt[tid][jt[r]]++;
  __syncthreads();
  if (tid < NT) {
    unsigned s = 0;
    for (int i = 0; i < 512; ++i) s += sm.cnt[i][tid];
    sm.tot[tid] = (int)s;
  }
  __syncthreads();
  if (tid == 0) {
    int acc = 0;
    for (int t = 0; t < NT; ++t) { sm.base[t] = acc; offs[t] = acc; acc += sm.tot[t]; }
    offs[NT] = acc;
  }
  __syncthreads();
  if (tid < NT) {
    unsigned run = (unsigned)sm.base[tid];
    for (int i = 0; i < 512; ++i) { unsigned c = sm.cnt[i][tid]; sm.cnt[i][tid] = run; run += c; }
  }
  __syncthreads();
  for (int r = r0; r < r1; ++r) {
    int t = jt[r];
    unsigned p = sm.cnt[tid][t]++;
    order[p] = r; tsv[p] = t;
  }
}

// ---------------- K5b: kmeans++ (single block, 1024 threads, 20 pts/thread in REGISTERS) ----
#define KPT 20
__global__ __launch_bounds__(1024) void k_km(const float* __restrict__ pos,
                                             const int* __restrict__ i0p,
                                             const float* __restrict__ Q,
                                             float* centsg) {
  __shared__ float red[16];
  __shared__ int   redi[16];
  __shared__ float Ssh;
  __shared__ int   bselsh;
  const int tid = threadIdx.x;
  const int lane = tid & 63, wv = tid >> 6;   // 16 waves
  float px[KPT], py[KPT], dm[KPT];
  const int i0 = *i0p;
  const float c0x = pos[2*i0], c0y = pos[2*i0+1];
  if (tid == 0) { centsg[0] = c0x; centsg[1] = c0y; }
  #pragma unroll
  for (int u = 0; u < KPT; ++u) {
    int i = tid + (u << 10);
    bool v = i < NPT;
    float x = v ? pos[2*i]   : 0.f;
    float y = v ? pos[2*i+1] : 0.f;
    px[u] = x; py[u] = y;
    float d = (x*x + y*y) + (c0x*c0x + c0y*c0y) - 2.f*(x*c0x + y*c0y);
    dm[u] = v ? fmaxf(d, 0.f) : 0.f;
  }
  __syncthreads();
  for (int s = 1; s < KC; ++s) {
    // --- S = sum(dm) ---
    float loc = 0.f;
    #pragma unroll
    for (int u = 0; u < KPT; ++u) loc += dm[u];
    for (int o = 32; o; o >>= 1) loc += __shfl_xor(loc, o, 64);
    if (lane == 0) red[wv] = loc;
    __syncthreads();
    if (tid == 0) {
      float S = 0.f;
      #pragma unroll
      for (int w = 0; w < 16; ++w) S += red[w];
      Ssh = S;
    }
    __syncthreads();
    const float invS = 1.0f/(Ssh + 1e-8f);
    // --- argmax (dm*invS + 1e-12) * Q ---
    float bsc = -3.4e38f; int bi = 0x7FFFFFFF;
    const float* Qs = Q + (size_t)s*NPT;
    #pragma unroll
    for (int u = 0; u < KPT; ++u) {
      int i = tid + (u << 10);
      if (i < NPT) {
        float sc = (dm[u]*invS + 1e-12f) * Qs[i];
        if (sc > bsc || (sc == bsc && i < bi)) { bsc = sc; bi = i; }
      }
    }
    for (int o = 32; o; o >>= 1) {
      float osc = __shfl_xor(bsc, o, 64);
      int   oid = __shfl_xor(bi, o, 64);
      if (osc > bsc || (osc == bsc && oid < bi)) { bsc = osc; bi = oid; }
    }
    __syncthreads();
    if (lane == 0) { red[wv] = bsc; redi[wv] = bi; }
    __syncthreads();
    if (tid == 0) {
      float bb = -3.4e38f; int bj = 0x7FFFFFFF;
      #pragma unroll
      for (int w = 0; w < 16; ++w) {
        float v2 = red[w]; int id2 = redi[w];
        if (v2 > bb || (v2 == bb && id2 < bj)) { bb = v2; bj = id2; }
      }
      bselsh = bj;
    }
    __syncthreads();
    const int sel = bselsh;
    const float cx = pos[2*sel], cy = pos[2*sel+1];
    if (tid == 0) { centsg[2*s] = cx; centsg[2*s+1] = cy; }
    #pragma unroll
    for (int u = 0; u < KPT; ++u) {
      float x = px[u], y = py[u];
      float d = (x*x + y*y) + (cx*cx + cy*cy) - 2.f*(x*cx + y*cy);
      dm[u] = fminf(dm[u], fmaxf(d, 0.f));
    }
    __syncthreads();
  }
}

// ---------------- K6: one Lloyd iteration (grid LGB=64) ----------------
__global__ __launch_bounds__(512) void k_lloyd(const float* __restrict__ pos,
                                               float* centsg, float* llp, int first) {
  const int b = blockIdx.x, tid = threadIdx.x, lane = tid & 63, wv = tid >> 6;
  __shared__ float cents[KC][2];
  __shared__ float comb[192];
  __shared__ float wpart[8][192];
  __shared__ int asg[CPB];
  if (tid < KC) { cents[tid][0] = centsg[2*tid]; cents[tid][1] = centsg[2*tid+1]; }
  __syncthreads();
  if (!first) {
    if (tid < 192) {
      float s = 0.f;
      for (int bb = 0; bb < LGB; ++bb) s += llp[bb*192 + tid];
      comb[tid] = s;
    }
    __syncthreads();
    if (tid < KC) {
      float cn = comb[128 + tid];
      if (cn > 0.f) {
        float dv = fmaxf(cn, 1.f);
        cents[tid][0] = comb[tid] / dv;
        cents[tid][1] = comb[64 + tid] / dv;
      }
    }
    __syncthreads();
    if (b == 0 && tid < KC) {   // benign same-value race
      centsg[2*tid] = cents[tid][0]; centsg[2*tid+1] = cents[tid][1];
    }
  }
  const int base = b*CPB;
  const int pcnt = max(0, min(NPT - base, CPB));
  if (tid < pcnt) {
    int i = base + tid;
    float x = pos[2*i], y = pos[2*i+1];
    float bd = 3.4e38f; int bj = 0;
    #pragma unroll 4
    for (int j = 0; j < KC; ++j) {
      float cx = cents[j][0], cy = cents[j][1];
      float d = (x*x + y*y) + (cx*cx + cy*cy) - 2.f*(x*cx + y*cy);
      d = fmaxf(d, 0.f);
      if (d < bd) { bd = d; bj = j; }
    }
    asg[tid] = bj;
  }
  __syncthreads();
  {
    int r0 = 40*wv, r1 = min(pcnt, r0 + 40);
    float sx = 0.f, sy = 0.f, cn = 0.f;
    for (int r = r0; r < r1; ++r) {
      int a = asg[r]; int i = base + r;
      float x = pos[2*i], y = pos[2*i+1];
      if (lane == a) { sx += x; sy += y; cn += 1.f; }
    }
    wpart[wv][lane] = sx; wpart[wv][64+lane] = sy; wpart[wv][128+lane] = cn;
  }
  __syncthreads();
  if (tid < 192) {
    float s = 0.f;
    #pragma unroll
    for (int w8 = 0; w8 < 8; ++w8) s += wpart[w8][tid];
    llp[b*192 + tid] = s;
  }
}

// ---------------- K7: final cent combine + cost build + run table (grid NBLK) ----------------
__global__ __launch_bounds__(512) void k_cb(const float* __restrict__ pos,
                                            const float* __restrict__ cl,
                                            const int* __restrict__ order,
                                            const int* __restrict__ tsv,
                                            const float* __restrict__ centsg,
                                            const float* __restrict__ llp,
                                            float* __restrict__ Ls, int* runT) {
  const int b = blockIdx.x, tid = threadIdx.x, lane = tid & 63, wv = tid >> 6;
  __shared__ float cents[KC][2];
  __shared__ float comb[192];
  if (tid < KC) { cents[tid][0] = centsg[2*tid]; cents[tid][1] = centsg[2*tid+1]; }
  __syncthreads();
  if (tid < 192) {
    float s = 0.f;
    for (int bb = 0; bb < LGB; ++bb) s += llp[bb*192 + tid];
    comb[tid] = s;
  }
  __syncthreads();
  if (tid < KC) {
    float cn = comb[128 + tid];
    if (cn > 0.f) {
      float dv = fmaxf(cn, 1.f);
      cents[tid][0] = comb[tid] / dv;
      cents[tid][1] = comb[64 + tid] / dv;
    }
  }
  if (tid == 0) {
    int nrun = 0, prev = -1;
    int rt[3] = {-1,-1,-1};
    for (int u = 0; u < RPB; ++u) {
      int t = tsv[b*RPB + u];
      if (t != prev) { if (nrun < 3) rt[nrun] = t; nrun++; prev = t; }
    }
    runT[b*3+0] = rt[0]; runT[b*3+1] = rt[1]; runT[b*3+2] = rt[2];
  }
  __syncthreads();
  #pragma unroll
  for (int k = 0; k < 10; ++k) {
    int ii = b*RPB + wv*10 + k;
    int od = order[ii];
    float x = pos[2*od], y = pos[2*od+1];
    float cx = cents[lane][0], cy = cents[lane][1];
    float cs = fmaxf((x*x + y*y) + (cx*cx + cy*cy) - 2.f*(x*cx + y*cy), 0.f);
    float cle = cl[(size_t)od*KC + lane];
    Ls[(size_t)ii*KC + lane] = -(cs + 0.5f*cle) / 0.05f;
  }
}

// ---------------- K8: one Sinkhorn iteration (grid NBLK) ----------------
template<int FIRST>
__global__ __launch_bounds__(512) void k_sink(const float* __restrict__ Ls,
                                              float* __restrict__ logu,
                                              const int* __restrict__ offs,
                                              const int* __restrict__ runT,
                                              const int* __restrict__ tsv,
                                              float* __restrict__ PMb, float* __restrict__ PSb,
                                              float* __restrict__ PLm, float* __restrict__ PLs) {
  const int b = blockIdx.x, tid = threadIdx.x, lane = tid & 63, wv = tid >> 6;
  __shared__ float lvs[3][64];
  __shared__ float wpm[8][2][64], wps[8][2][64];
  __shared__ int   wri[8][2];
  __shared__ float plmw[8], plsw[8];
  __shared__ float lvl_sh;
  const int rt0 = runT[b*3+0], rt1 = runT[b*3+1], rt2 = runT[b*3+2];

  if (!FIRST) {
    if (wv < 3) {
      int t = (wv == 0) ? rt0 : ((wv == 1) ? rt1 : rt2);
      if (t >= 0) {
        float m = -3.4e38f, s = 0.f;
        int bb0 = offs[t] / RPB, bb1 = (offs[t+1] - 1) / RPB;
        for (int bb = bb0; bb <= bb1; ++bb) {
          #pragma unroll
          for (int q = 0; q < 3; ++q) {
            if (runT[bb*3+q] == t)
              lse_merge(m, s, PMb[(bb*3+q)*64 + lane], PSb[(bb*3+q)*64 + lane]);
          }
        }
        lvs[wv][lane] = -(__logf(s) + m);
      }
    } else if (wv == 3) {
      float m = -3.4e38f, s = 0.f;
      for (int bb = lane; bb < NBLK; bb += 64) lse_merge(m, s, PLm[bb], PLs[bb]);
      for (int o = 32; o; o >>= 1) {
        float m2 = __shfl_xor(m, o, 64), s2 = __shfl_xor(s, o, 64);
        lse_merge(m, s, m2, s2);
      }
      if (lane == 0) lvl_sh = logf((float)(NPT - NSLOT)) - (__logf(s) + m);
    }
    __syncthreads();
  }
  const float lvl = FIRST ? 0.f : lvl_sh;

  float am0 = -3.4e38f, as0 = 0.f, am1 = -3.4e38f, as1 = 0.f;
  int r0i = -1, r1i = -1;
  float lm = -3.4e38f, lss = 0.f;
  #pragma unroll
  for (int k = 0; k < 10; ++k) {
    int ii = b*RPB + wv*10 + k;
    int t = tsv[ii];
    int rq = (t == rt0) ? 0 : ((t == rt1) ? 1 : 2);
    float lvv = FIRST ? 0.f : lvs[rq][lane];
    float Lv = Ls[(size_t)ii*KC + lane];
    float x = Lv + lvv;
    float m = x;
    for (int o = 32; o; o >>= 1) m = fmaxf(m, __shfl_xor(m, o, 64));
    m = fmaxf(m, lvl);
    float e = __expf(x - m);
    for (int o = 32; o; o >>= 1) e += __shfl_xor(e, o, 64);
    e += __expf(lvl - m);
    float lu = -(__logf(e) + m);
    if (lane == 0) logu[ii] = lu;
    float cv = Lv + lu;
    if (r0i < 0 || rq == r0i) { r0i = rq; lse_merge(am0, as0, cv, 1.0f); }
    else                      { r1i = rq; lse_merge(am1, as1, cv, 1.0f); }
    lse_merge(lm, lss, lu, 1.0f);
  }
  wpm[wv][0][lane] = am0; wps[wv][0][lane] = as0;
  wpm[wv][1][lane] = am1; wps[wv][1][lane] = as1;
  if (lane == 0) { wri[wv][0] = r0i; wri[wv][1] = r1i; plmw[wv] = lm; plsw[wv] = lss; }
  __syncthreads();
  if (wv < 3) {
    float m = -3.4e38f, s = 0.f;
    for (int w8 = 0; w8 < 8; ++w8) {
      if (wri[w8][0] == wv) lse_merge(m, s, wpm[w8][0][lane], wps[w8][0][lane]);
      if (wri[w8][1] == wv) lse_merge(m, s, wpm[w8][1][lane], wps[w8][1][lane]);
    }
    PMb[(b*3+wv)*64 + lane] = m; PSb[(b*3+wv)*64 + lane] = s;
  } else if (wv == 3 && lane == 0) {
    float m = -3.4e38f, s = 0.f;
    #pragma unroll
    for (int w8 = 0; w8 < 8; ++w8) lse_merge(m, s, plmw[w8], plsw[w8]);
    PLm[b] = m; PLs[b] = s;
  }
}

// ---------------- K9: final log_v + vals ----------------
__global__ __launch_bounds__(512) void k_fin(const float* __restrict__ Ls,
                                             const float* __restrict__ logu,
                                             const int* __restrict__ offs,
                                             const int* __restrict__ runT,
                                             const int* __restrict__ tsv,
                                             const int* __restrict__ order,
                                             const float* __restrict__ PMb,
                                             const float* __restrict__ PSb,
                                             float* __restrict__ vals) {
  const int b = blockIdx.x, tid = threadIdx.x, lane = tid & 63, wv = tid >> 6;
  __shared__ float lvs[3][64];
  const int rt0 = runT[b*3+0], rt1 = runT[b*3+1], rt2 = runT[b*3+2];
  if (wv < 3) {
    int t = (wv == 0) ? rt0 : ((wv == 1) ? rt1 : rt2);
    if (t >= 0) {
      float m = -3.4e38f, s = 0.f;
      int bb0 = offs[t] / RPB, bb1 = (offs[t+1] - 1) / RPB;
      for (int bb = bb0; bb <= bb1; ++bb) {
        #pragma unroll
        for (int q = 0; q < 3; ++q) {
          if (runT[bb*3+q] == t)
            lse_merge(m, s, PMb[(bb*3+q)*64 + lane], PSb[(bb*3+q)*64 + lane]);
        }
      }
      lvs[wv][lane] = -(__logf(s) + m);
    }
  }
  __syncthreads();
  #pragma unroll
  for (int k = 0; k < 10; ++k) {
    int ii = b*RPB + wv*10 + k;
    int t = tsv[ii];
    int rq = (t == rt0) ? 0 : ((t == rt1) ? 1 : 2);
    vals[(size_t)order[ii]*KC + lane] =
        __expf(Ls[(size_t)ii*KC + lane] + lvs[rq][lane] + logu[ii]);
  }
}

// ---------------- K10: expand vals into full T ----------------
__global__ __launch_bounds__(256) void k_T(const float* __restrict__ vals,
                                           const int* __restrict__ jt,
                                           float* __restrict__ T) {
  __shared__ float v[KC];
  const int i = blockIdx.x;
  const int tid = threadIdx.x;
  if (tid < KC) v[tid] = vals[(size_t)i*KC + tid];
  __syncthreads();
  const int t = jt[i];
  for (int e = tid; e < NSLOT; e += 256) {
    int j = e / NT;
    int tt = e - j*NT;
    T[(size_t)i*NSLOT + e] = (tt == t) ? v[j] : 0.0f;
  }
}

// ---------------- K11: logits = log(vals + 1e-8) ----------------
__global__ __launch_bounds__(256) void k_logits(float* logits) {
  int idx = blockIdx.x*256 + threadIdx.x;
  if (idx < NPT*KC) logits[idx] = logf(logits[idx] + 1e-8f);
}

extern "C" void kernel_launch(void* const* d_in, const int* in_sizes, int n_in,
                              void* d_out, int out_size, void* d_ws, size_t ws_size,
                              hipStream_t stream) {
  const float* emb    = (const float*)d_in[0];
  const float* pos    = (const float*)d_in[1];
  const float* W1     = (const float*)d_in[2];
  const float* b1     = (const float*)d_in[3];
  const float* protos = (const float*)d_in[4];
  const int*   jt     = (const int*)d_in[5];

  float* out  = (float*)d_out;
  float* vals = out;
  float* T    = out + (size_t)NPT*KC;
  float* TS   = T;

  unsigned* sub = (unsigned*)(TS + OFF_SUB);
  int* i0p    = (int*)(TS + OFF_I0);
  int* order  = (int*)(TS + OFF_ORDER);
  int* tsv    = (int*)(TS + OFF_TSV);
  int* offs   = (int*)(TS + OFF_OFFS);
  int* runT   = (int*)(TS + OFF_RUNT);
  float* centsg = TS + OFF_CENTS;
  float* llp  = TS + OFF_LLP;
  float* Ls   = TS + OFF_LS;
  float* logu = TS + OFF_LOGU;
  float* PMb  = TS + OFF_PMB;
  float* PSb  = TS + OFF_PSB;
  float* PLm  = TS + OFF_PLM;
  float* PLs  = TS + OFF_PLS;

  hipLaunchKernelGGL(k_keys, dim3(1), dim3(64), 0, stream, sub, i0p);
  hipLaunchKernelGGL(k_gumbel, dim3((NPT + 255)/256, KC - 1), dim3(256), 0, stream,
                     sub, TS + OFF_Q);
  hipLaunchKernelGGL(k_gemm, dim3((NPT + 63)/64), dim3(256), 0, stream,
                     emb, W1, b1, TS + OFF_H);
  hipLaunchKernelGGL(k_cl, dim3((NPT + 3)/4), dim3(256), 0, stream,
                     TS + OFF_H, protos, TS + OFF_CL);
  hipLaunchKernelGGL(k_sort, dim3(1), dim3(512), 0, stream, jt, order, tsv, offs);
  hipLaunchKernelGGL(k_km, dim3(1), dim3(1024), 0, stream,
                     pos, i0p, TS + OFF_Q, centsg);

  for (int it = 0; it < 10; ++it)
    hipLaunchKernelGGL(k_lloyd, dim3(LGB), dim3(512), 0, stream,
                       pos, centsg, llp, (it == 0) ? 1 : 0);

  hipLaunchKernelGGL(k_cb, dim3(NBLK), dim3(512), 0, stream,
                     pos, TS + OFF_CL, order, tsv, centsg, llp, Ls, runT);

  hipLaunchKernelGGL(k_sink<1>, dim3(NBLK), dim3(512), 0, stream,
                     Ls, logu, offs, runT, tsv, PMb, PSb, PLm, PLs);
  for (int it = 1; it < SINK_IT; ++it)
    hipLaunchKernelGGL(k_sink<0>, dim3(NBLK), dim3(512), 0, stream,
                       Ls, logu, offs, runT, tsv, PMb, PSb, PLm, PLs);

  hipLaunchKernelGGL(k_fin, dim3(NBLK), dim3(512), 0, stream,
                     Ls, logu, offs, runT, tsv, order, PMb, PSb, vals);

  hipLaunchKernelGGL(k_T, dim3(NPT), dim3(256), 0, stream, vals, jt, T);
  hipLaunchKernelGGL(k_logits, dim3((NPT*KC + 255)/256), dim3(256), 0, stream, vals);
}

// Round 9
// 1739.316 us; speedup vs baseline: 14.0550x; 1.0739x over previous
//
#include <hip/hip_runtime.h>

#define NPT 20000
#define DIMK 256
#define HD 128
#define KC 64
#define NT 17
#define NSLOT (KC*NT)          // 1088
#define SINK_IT 50
#define NBLK 250               // sinkhorn/cb blocks: 80 rows each
#define RPB 80
#define LGB 64                 // lloyd blocks
#define CPB 313                // lloyd points per block (64*313 >= 20000)

// ---- scratch offsets (floats) inside the T region of d_out ----
#define OFF_H     0
#define OFF_CL    (NPT*HD)                   // 2,560,000
#define OFF_Q     (OFF_CL + NPT*KC)
#define OFF_LS    (OFF_Q + KC*NPT)
#define OFF_LOGU  (OFF_LS + NPT*KC)
#define OFF_ORDER (OFF_LOGU + NPT)
#define OFF_TSV   (OFF_ORDER + NPT)
#define OFF_OFFS  (OFF_TSV + NPT)            // 32 ints
#define OFF_CENTS (OFF_OFFS + 32)            // 128 f
#define OFF_I0    (OFF_CENTS + 128)
#define OFF_SUB   (OFF_I0 + 32)
#define OFF_LLP   (OFF_SUB + 128)            // LGB*192
#define OFF_PMB   (OFF_LLP + LGB*192)        // NBLK*3*64 = 48000
#define OFF_PSB   (OFF_PMB + NBLK*3*64)
#define OFF_RUNT  (OFF_PSB + NBLK*3*64)      // 750 ints -> 768
#define OFF_PLM   (OFF_RUNT + 768)           // 256
#define OFF_PLS   (OFF_PLM + 256)            // 256
// end ~= 6.53M floats << 21.76M floats of T region

__device__ __forceinline__ void tf2x32(unsigned k0, unsigned k1,
                                       unsigned x0, unsigned x1,
                                       unsigned& o0, unsigned& o1) {
  unsigned ks0 = k0, ks1 = k1, ks2 = k0 ^ k1 ^ 0x1BD11BDAu;
  x0 += ks0; x1 += ks1;
  const int rot[2][4] = {{13,15,26,6},{17,29,16,24}};
  unsigned ks[3] = {ks0, ks1, ks2};
  #pragma unroll
  for (int i = 0; i < 5; ++i) {
    #pragma unroll
    for (int r = 0; r < 4; ++r) {
      int rr = rot[i & 1][r];
      x0 += x1;
      x1 = (x1 << rr) | (x1 >> (32 - rr));
      x1 ^= x0;
    }
    x0 += ks[(i+1)%3];
    x1 += ks[(i+2)%3] + (unsigned)(i+1);
  }
  o0 = x0; o1 = x1;
}

__device__ __forceinline__ void lse_merge(float& m, float& s, float m2, float s2) {
  float mn = fmaxf(m, m2);
  s = s*__expf(m - mn) + s2*__expf(m2 - mn);
  m = mn;
}

// ---------------- K1: key chain + randint i0 (verified R5) ----------------
__global__ void k_keys(unsigned* sub, int* i0p) {
  if (threadIdx.x != 0 || blockIdx.x != 0) return;
  unsigned key0 = 0u, key1 = 42u;
  unsigned c0, c1, s0, s1;
  tf2x32(key0, key1, 0u, 0u, c0, c1);
  tf2x32(key0, key1, 0u, 1u, s0, s1);
  key0 = c0; key1 = c1;
  unsigned k1a, k1b, k2a, k2b;
  tf2x32(s0, s1, 0u, 0u, k1a, k1b);
  tf2x32(s0, s1, 0u, 1u, k2a, k2b);
  unsigned h0, h1, l0, l1;
  tf2x32(k1a, k1b, 0u, 0u, h0, h1);
  tf2x32(k2a, k2b, 0u, 0u, l0, l1);
  unsigned hb = h0 ^ h1, lb = l0 ^ l1;
  unsigned span = 20000u;
  unsigned m1 = 65536u % span;
  unsigned mult = (unsigned)(((unsigned long long)m1 * m1) % span);  // 7296
  unsigned off32 = (hb % span) * mult + (lb % span);
  *i0p = (int)(off32 % span);
  sub[0] = 0u; sub[1] = 0u;
  for (int i = 1; i < KC; ++i) {
    tf2x32(key0, key1, 0u, 0u, c0, c1);
    tf2x32(key0, key1, 0u, 1u, s0, s1);
    key0 = c0; key1 = c1;
    sub[2*i] = s0; sub[2*i+1] = s1;
  }
}

// ---------------- K2: Q[step][i] = exp(gumbel) = -1/log(u) ----------------
__global__ __launch_bounds__(256) void k_gumbel(const unsigned* __restrict__ sub,
                                                float* __restrict__ Q) {
  int s = blockIdx.y + 1;
  int i = blockIdx.x * 256 + threadIdx.x;
  if (i >= NPT) return;
  unsigned o0, o1;
  tf2x32(sub[2*s], sub[2*s+1], 0u, (unsigned)i, o0, o1);
  unsigned bits = o0 ^ o1;
  unsigned fb = (bits >> 9) | 0x3f800000u;
  float u = __uint_as_float(fb) - 1.0f;
  if (u == 0.0f) u = 1.17549435e-38f;
  Q[(size_t)s*NPT + i] = -1.0f / logf(u);
}

// ---------------- K3: h = selu(emb @ W1 + b1) ----------------
__global__ __launch_bounds__(256) void k_gemm(const float* __restrict__ emb,
                                              const float* __restrict__ W1,
                                              const float* __restrict__ b1,
                                              float* __restrict__ h) {
  __shared__ float As[64][64];
  __shared__ float Bs[64][HD];
  const int m0 = blockIdx.x * 64;
  const int tid = threadIdx.x;
  const int tx = tid & 31;
  const int ty = tid >> 5;
  float acc[8][4];
  #pragma unroll
  for (int a = 0; a < 8; ++a)
    #pragma unroll
    for (int c = 0; c < 4; ++c) acc[a][c] = 0.f;

  for (int kc = 0; kc < DIMK; kc += 64) {
    #pragma unroll
    for (int it = 0; it < 4; ++it) {
      int f = it*256 + tid;
      int r = f >> 4;
      int kk = (f & 15) << 2;
      float4 v = make_float4(0.f,0.f,0.f,0.f);
      if (m0 + r < NPT)
        v = *(const float4*)(emb + (size_t)(m0 + r)*DIMK + kc + kk);
      As[kk+0][r] = v.x; As[kk+1][r] = v.y; As[kk+2][r] = v.z; As[kk+3][r] = v.w;
    }
    #pragma unroll
    for (int it = 0; it < 8; ++it) {
      int f = it*256 + tid;
      int kk = f >> 5;
      int cc = (f & 31) << 2;
      *(float4*)&Bs[kk][cc] = *(const float4*)(W1 + (size_t)(kc + kk)*HD + cc);
    }
    __syncthreads();
    #pragma unroll 8
    for (int kk = 0; kk < 64; ++kk) {
      float4 a0 = *(float4*)&As[kk][ty*8];
      float4 a1 = *(float4*)&As[kk][ty*8+4];
      float4 bb = *(float4*)&Bs[kk][tx*4];
      float av[8] = {a0.x,a0.y,a0.z,a0.w,a1.x,a1.y,a1.z,a1.w};
      float bv[4] = {bb.x,bb.y,bb.z,bb.w};
      #pragma unroll
      for (int a = 0; a < 8; ++a)
        #pragma unroll
        for (int c = 0; c < 4; ++c) acc[a][c] += av[a]*bv[c];
    }
    __syncthreads();
  }
  const float SC = 1.0507009873554805f, AL = 1.6732632423543772f;
  #pragma unroll
  for (int a = 0; a < 8; ++a) {
    int r = m0 + ty*8 + a;
    if (r >= NPT) continue;
    float4 o;
    float* po = &o.x;
    #pragma unroll
    for (int c = 0; c < 4; ++c) {
      float x = acc[a][c] + b1[tx*4 + c];
      float v = (x > 0.f) ? x : AL * expm1f(x);
      po[c] = SC * v;
    }
    *(float4*)(h + (size_t)r*HD + tx*4) = o;
  }
}

// ---------------- K4: c_learned = sqdist(h, protos[:64]) ----------------
__global__ __launch_bounds__(256) void k_cl(const float* __restrict__ h,
                                            const float* __restrict__ protos,
                                            float* __restrict__ cl) {
  __shared__ float ps[KC][129];
  __shared__ float hs[4][HD];
  const int tid = threadIdx.x;
  #pragma unroll
  for (int it = 0; it < 32; ++it) {
    int f = it*256 + tid;
    ps[f >> 7][f & 127] = protos[f];
  }
  const int i0r = blockIdx.x * 4;
  for (int f = tid; f < 4*HD; f += 256) {
    int rr = f >> 7, d = f & 127;
    int gi = i0r + rr;
    hs[rr][d] = (gi < NPT) ? h[(size_t)gi*HD + d] : 0.f;
  }
  __syncthreads();
  const int j = tid & 63, rq = tid >> 6;
  const int gi = i0r + rq;
  if (gi < NPT) {
    float dot = 0.f, hh = 0.f, pp = 0.f;
    #pragma unroll 8
    for (int d = 0; d < HD; ++d) {
      float a = hs[rq][d], b = ps[j][d];
      dot += a*b; hh += a*a; pp += b*b;
    }
    float c = hh + pp - 2.f*dot;
    cl[(size_t)gi*KC + j] = fmaxf(c, 0.f);
  }
}

// ---------------- K5a: stable counting sort by joint type (single block) ----------------
__global__ __launch_bounds__(512) void k_sort(const int* __restrict__ jt,
                                              int* order, int* tsv, int* offs) {
  __shared__ struct { unsigned cnt[512][NT]; int tot[NT]; int base[NT]; } sm;
  const int tid = threadIdx.x;
  const int CHS = 40;
  const int r0 = tid*CHS, r1 = min(NPT, r0 + CHS);
  for (int t = 0; t < NT; ++t) sm.cnt[tid][t] = 0;
  __syncthreads();
  for (int r = r0; r < r1; ++r) sm.cnt[tid][jt[r]]++;
  __syncthreads();
  if (tid < NT) {
    unsigned s = 0;
    for (int i = 0; i < 512; ++i) s += sm.cnt[i][tid];
    sm.tot[tid] = (int)s;
  }
  __syncthreads();
  if (tid == 0) {
    int acc = 0;
    for (int t = 0; t < NT; ++t) { sm.base[t] = acc; offs[t] = acc; acc += sm.tot[t]; }
    offs[NT] = acc;
  }
  __syncthreads();
  if (tid < NT) {
    unsigned run = (unsigned)sm.base[tid];
    for (int i = 0; i < 512; ++i) { unsigned c = sm.cnt[i][tid]; sm.cnt[i][tid] = run; run += c; }
  }
  __syncthreads();
  for (int r = r0; r < r1; ++r) {
    int t = jt[r];
    unsigned p = sm.cnt[tid][t]++;
    order[p] = r; tsv[p] = t;
  }
}

// ---------------- K5b: kmeans++ — registers via (1024,4); NO S-reduction ----------------
// argmax((dm/(S+1e-8) + 1e-12)*Q) == argmax(dm*Q) except for dm==0 points, which need a
// ~e^-21 gumbel tail event to win (negligible). One fused update+score pass per step.
#define KPT 20
__global__ __launch_bounds__(1024, 4) void k_km(const float* __restrict__ pos,
                                                const int* __restrict__ i0p,
                                                const float* __restrict__ Q,
                                                float* centsg) {
  __shared__ float red[16];
  __shared__ int   redi[16];
  __shared__ int   bselsh;
  const int tid = threadIdx.x;
  const int lane = tid & 63, wv = tid >> 6;   // 16 waves
  float px[KPT], py[KPT], dm[KPT];
  const int i0 = *i0p;
  float cx = pos[2*i0], cy = pos[2*i0+1];
  if (tid == 0) { centsg[0] = cx; centsg[1] = cy; }
  #pragma unroll
  for (int u = 0; u < KPT; ++u) {
    int i = tid + (u << 10);
    bool v = i < NPT;
    px[u] = v ? pos[2*i]   : 0.f;
    py[u] = v ? pos[2*i+1] : 0.f;
    dm[u] = 3.4e38f;
  }
  for (int s = 1; s < KC; ++s) {
    const float* Qs = Q + (size_t)s*NPT;
    const float cc2 = cx*cx + cy*cy;
    float bsc = -3.4e38f; int bi = 0x7FFFFFFF;
    #pragma unroll
    for (int u = 0; u < KPT; ++u) {
      int i = tid + (u << 10);
      float x = px[u], y = py[u];
      float d = fmaxf((x*x + y*y) + cc2 - 2.f*(x*cx + y*cy), 0.f);
      float nd = fminf(dm[u], d);
      dm[u] = nd;
      if (i < NPT) {
        float sc = nd * Qs[i];
        if (sc > bsc || (sc == bsc && i < bi)) { bsc = sc; bi = i; }
      }
    }
    for (int o = 32; o; o >>= 1) {
      float osc = __shfl_xor(bsc, o, 64);
      int   oid = __shfl_xor(bi, o, 64);
      if (osc > bsc || (osc == bsc && oid < bi)) { bsc = osc; bi = oid; }
    }
    if (lane == 0) { red[wv] = bsc; redi[wv] = bi; }
    __syncthreads();
    if (tid == 0) {
      float bb = -3.4e38f; int bj = 0x7FFFFFFF;
      #pragma unroll
      for (int w = 0; w < 16; ++w) {
        float v2 = red[w]; int id2 = redi[w];
        if (v2 > bb || (v2 == bb && id2 < bj)) { bb = v2; bj = id2; }
      }
      bselsh = bj;
    }
    __syncthreads();
    const int sel = bselsh;
    cx = pos[2*sel]; cy = pos[2*sel+1];
    if (tid == 0) { centsg[2*s] = cx; centsg[2*s+1] = cy; }
    __syncthreads();
  }
}

// ---------------- K6: one Lloyd iteration (grid LGB=64) ----------------
__global__ __launch_bounds__(512) void k_lloyd(const float* __restrict__ pos,
                                               float* centsg, float* llp, int first) {
  const int b = blockIdx.x, tid = threadIdx.x, lane = tid & 63, wv = tid >> 6;
  __shared__ float cents[KC][2];
  __shared__ float comb[192];
  __shared__ float wpart[8][192];
  __shared__ int asg[CPB];
  if (tid < KC) { cents[tid][0] = centsg[2*tid]; cents[tid][1] = centsg[2*tid+1]; }
  __syncthreads();
  if (!first) {
    if (tid < 192) {
      float s = 0.f;
      for (int bb = 0; bb < LGB; ++bb) s += llp[bb*192 + tid];
      comb[tid] = s;
    }
    __syncthreads();
    if (tid < KC) {
      float cn = comb[128 + tid];
      if (cn > 0.f) {
        float dv = fmaxf(cn, 1.f);
        cents[tid][0] = comb[tid] / dv;
        cents[tid][1] = comb[64 + tid] / dv;
      }
    }
    __syncthreads();
    if (b == 0 && tid < KC) {   // benign same-value race
      centsg[2*tid] = cents[tid][0]; centsg[2*tid+1] = cents[tid][1];
    }
  }
  const int base = b*CPB;
  const int pcnt = max(0, min(NPT - base, CPB));
  if (tid < pcnt) {
    int i = base + tid;
    float x = pos[2*i], y = pos[2*i+1];
    float bd = 3.4e38f; int bj = 0;
    #pragma unroll 4
    for (int j = 0; j < KC; ++j) {
      float cx = cents[j][0], cy = cents[j][1];
      float d = (x*x + y*y) + (cx*cx + cy*cy) - 2.f*(x*cx + y*cy);
      d = fmaxf(d, 0.f);
      if (d < bd) { bd = d; bj = j; }
    }
    asg[tid] = bj;
  }
  __syncthreads();
  {
    int r0 = 40*wv, r1 = min(pcnt, r0 + 40);
    float sx = 0.f, sy = 0.f, cn = 0.f;
    for (int r = r0; r < r1; ++r) {
      int a = asg[r]; int i = base + r;
      float x = pos[2*i], y = pos[2*i+1];
      if (lane == a) { sx += x; sy += y; cn += 1.f; }
    }
    wpart[wv][lane] = sx; wpart[wv][64+lane] = sy; wpart[wv][128+lane] = cn;
  }
  __syncthreads();
  if (tid < 192) {
    float s = 0.f;
    #pragma unroll
    for (int w8 = 0; w8 < 8; ++w8) s += wpart[w8][tid];
    llp[b*192 + tid] = s;
  }
}

// ---------------- K7: final cent combine + cost build + run table (grid NBLK) ----------------
__global__ __launch_bounds__(512) void k_cb(const float* __restrict__ pos,
                                            const float* __restrict__ cl,
                                            const int* __restrict__ order,
                                            const int* __restrict__ tsv,
                                            const float* __restrict__ centsg,
                                            const float* __restrict__ llp,
                                            float* __restrict__ Ls, int* runT) {
  const int b = blockIdx.x, tid = threadIdx.x, lane = tid & 63, wv = tid >> 6;
  __shared__ float cents[KC][2];
  __shared__ float comb[192];
  if (tid < KC) { cents[tid][0] = centsg[2*tid]; cents[tid][1] = centsg[2*tid+1]; }
  __syncthreads();
  if (tid < 192) {
    float s = 0.f;
    for (int bb = 0; bb < LGB; ++bb) s += llp[bb*192 + tid];
    comb[tid] = s;
  }
  __syncthreads();
  if (tid < KC) {
    float cn = comb[128 + tid];
    if (cn > 0.f) {
      float dv = fmaxf(cn, 1.f);
      cents[tid][0] = comb[tid] / dv;
      cents[tid][1] = comb[64 + tid] / dv;
    }
  }
  if (tid == 0) {
    int nrun = 0, prev = -1;
    int rt[3] = {-1,-1,-1};
    for (int u = 0; u < RPB; ++u) {
      int t = tsv[b*RPB + u];
      if (t != prev) { if (nrun < 3) rt[nrun] = t; nrun++; prev = t; }
    }
    runT[b*3+0] = rt[0]; runT[b*3+1] = rt[1]; runT[b*3+2] = rt[2];
  }
  __syncthreads();
  #pragma unroll
  for (int k = 0; k < 10; ++k) {
    int ii = b*RPB + wv*10 + k;
    int od = order[ii];
    float x = pos[2*od], y = pos[2*od+1];
    float cx = cents[lane][0], cy = cents[lane][1];
    float cs = fmaxf((x*x + y*y) + (cx*cx + cy*cy) - 2.f*(x*cx + y*cy), 0.f);
    float cle = cl[(size_t)od*KC + lane];
    Ls[(size_t)ii*KC + lane] = -(cs + 0.5f*cle) / 0.05f;
  }
}

// ---------------- K8: one Sinkhorn iteration (grid NBLK) ----------------
template<int FIRST>
__global__ __launch_bounds__(512) void k_sink(const float* __restrict__ Ls,
                                              float* __restrict__ logu,
                                              const int* __restrict__ offs,
                                              const int* __restrict__ runT,
                                              const int* __restrict__ tsv,
                                              float* __restrict__ PMb, float* __restrict__ PSb,
                                              float* __restrict__ PLm, float* __restrict__ PLs) {
  const int b = blockIdx.x, tid = threadIdx.x, lane = tid & 63, wv = tid >> 6;
  __shared__ float lvs[3][64];
  __shared__ float wpm[8][2][64], wps[8][2][64];
  __shared__ int   wri[8][2];
  __shared__ float plmw[8], plsw[8];
  __shared__ float lvl_sh;
  const int rt0 = runT[b*3+0], rt1 = runT[b*3+1], rt2 = runT[b*3+2];

  if (!FIRST) {
    if (wv < 3) {
      int t = (wv == 0) ? rt0 : ((wv == 1) ? rt1 : rt2);
      if (t >= 0) {
        float m = -3.4e38f, s = 0.f;
        int bb0 = offs[t] / RPB, bb1 = (offs[t+1] - 1) / RPB;
        for (int bb = bb0; bb <= bb1; ++bb) {
          #pragma unroll
          for (int q = 0; q < 3; ++q) {
            if (runT[bb*3+q] == t)
              lse_merge(m, s, PMb[(bb*3+q)*64 + lane], PSb[(bb*3+q)*64 + lane]);
          }
        }
        lvs[wv][lane] = -(__logf(s) + m);
      }
    } else if (wv == 3) {
      float m = -3.4e38f, s = 0.f;
      for (int bb = lane; bb < NBLK; bb += 64) lse_merge(m, s, PLm[bb], PLs[bb]);
      for (int o = 32; o; o >>= 1) {
        float m2 = __shfl_xor(m, o, 64), s2 = __shfl_xor(s, o, 64);
        lse_merge(m, s, m2, s2);
      }
      if (lane == 0) lvl_sh = logf((float)(NPT - NSLOT)) - (__logf(s) + m);
    }
    __syncthreads();
  }
  const float lvl = FIRST ? 0.f : lvl_sh;

  float am0 = -3.4e38f, as0 = 0.f, am1 = -3.4e38f, as1 = 0.f;
  int r0i = -1, r1i = -1;
  float lm = -3.4e38f, lss = 0.f;
  #pragma unroll
  for (int k = 0; k < 10; ++k) {
    int ii = b*RPB + wv*10 + k;
    int t = tsv[ii];
    int rq = (t == rt0) ? 0 : ((t == rt1) ? 1 : 2);
    float lvv = FIRST ? 0.f : lvs[rq][lane];
    float Lv = Ls[(size_t)ii*KC + lane];
    float x = Lv + lvv;
    float m = x;
    for (int o = 32; o; o >>= 1) m = fmaxf(m, __shfl_xor(m, o, 64));
    m = fmaxf(m, lvl);
    float e = __expf(x - m);
    for (int o = 32; o; o >>= 1) e += __shfl_xor(e, o, 64);
    e += __expf(lvl - m);
    float lu = -(__logf(e) + m);
    if (lane == 0) logu[ii] = lu;
    float cv = Lv + lu;
    if (r0i < 0 || rq == r0i) { r0i = rq; lse_merge(am0, as0, cv, 1.0f); }
    else                      { r1i = rq; lse_merge(am1, as1, cv, 1.0f); }
    lse_merge(lm, lss, lu, 1.0f);
  }
  wpm[wv][0][lane] = am0; wps[wv][0][lane] = as0;
  wpm[wv][1][lane] = am1; wps[wv][1][lane] = as1;
  if (lane == 0) { wri[wv][0] = r0i; wri[wv][1] = r1i; plmw[wv] = lm; plsw[wv] = lss; }
  __syncthreads();
  if (wv < 3) {
    float m = -3.4e38f, s = 0.f;
    for (int w8 = 0; w8 < 8; ++w8) {
      if (wri[w8][0] == wv) lse_merge(m, s, wpm[w8][0][lane], wps[w8][0][lane]);
      if (wri[w8][1] == wv) lse_merge(m, s, wpm[w8][1][lane], wps[w8][1][lane]);
    }
    PMb[(b*3+wv)*64 + lane] = m; PSb[(b*3+wv)*64 + lane] = s;
  } else if (wv == 3 && lane == 0) {
    float m = -3.4e38f, s = 0.f;
    #pragma unroll
    for (int w8 = 0; w8 < 8; ++w8) lse_merge(m, s, plmw[w8], plsw[w8]);
    PLm[b] = m; PLs[b] = s;
  }
}

// ---------------- K9: final log_v + vals ----------------
__global__ __launch_bounds__(512) void k_fin(const float* __restrict__ Ls,
                                             const float* __restrict__ logu,
                                             const int* __restrict__ offs,
                                             const int* __restrict__ runT,
                                             const int* __restrict__ tsv,
                                             const int* __restrict__ order,
                                             const float* __restrict__ PMb,
                                             const float* __restrict__ PSb,
                                             float* __restrict__ vals) {
  const int b = blockIdx.x, tid = threadIdx.x, lane = tid & 63, wv = tid >> 6;
  __shared__ float lvs[3][64];
  const int rt0 = runT[b*3+0], rt1 = runT[b*3+1], rt2 = runT[b*3+2];
  if (wv < 3) {
    int t = (wv == 0) ? rt0 : ((wv == 1) ? rt1 : rt2);
    if (t >= 0) {
      float m = -3.4e38f, s = 0.f;
      int bb0 = offs[t] / RPB, bb1 = (offs[t+1] - 1) / RPB;
      for (int bb = bb0; bb <= bb1; ++bb) {
        #pragma unroll
        for (int q = 0; q < 3; ++q) {
          if (runT[bb*3+q] == t)
            lse_merge(m, s, PMb[(bb*3+q)*64 + lane], PSb[(bb*3+q)*64 + lane]);
        }
      }
      lvs[wv][lane] = -(__logf(s) + m);
    }
  }
  __syncthreads();
  #pragma unroll
  for (int k = 0; k < 10; ++k) {
    int ii = b*RPB + wv*10 + k;
    int t = tsv[ii];
    int rq = (t == rt0) ? 0 : ((t == rt1) ? 1 : 2);
    vals[(size_t)order[ii]*KC + lane] =
        __expf(Ls[(size_t)ii*KC + lane] + lvs[rq][lane] + logu[ii]);
  }
}

// ---------------- K10: expand vals into full T ----------------
__global__ __launch_bounds__(256) void k_T(const float* __restrict__ vals,
                                           const int* __restrict__ jt,
                                           float* __restrict__ T) {
  __shared__ float v[KC];
  const int i = blockIdx.x;
  const int tid = threadIdx.x;
  if (tid < KC) v[tid] = vals[(size_t)i*KC + tid];
  __syncthreads();
  const int t = jt[i];
  for (int e = tid; e < NSLOT; e += 256) {
    int j = e / NT;
    int tt = e - j*NT;
    T[(size_t)i*NSLOT + e] = (tt == t) ? v[j] : 0.0f;
  }
}

// ---------------- K11: logits = log(vals + 1e-8) ----------------
__global__ __launch_bounds__(256) void k_logits(float* logits) {
  int idx = blockIdx.x*256 + threadIdx.x;
  if (idx < NPT*KC) logits[idx] = logf(logits[idx] + 1e-8f);
}

extern "C" void kernel_launch(void* const* d_in, const int* in_sizes, int n_in,
                              void* d_out, int out_size, void* d_ws, size_t ws_size,
                              hipStream_t stream) {
  const float* emb    = (const float*)d_in[0];
  const float* pos    = (const float*)d_in[1];
  const float* W1     = (const float*)d_in[2];
  const float* b1     = (const float*)d_in[3];
  const float* protos = (const float*)d_in[4];
  const int*   jt     = (const int*)d_in[5];

  float* out  = (float*)d_out;
  float* vals = out;
  float* T    = out + (size_t)NPT*KC;
  float* TS   = T;

  unsigned* sub = (unsigned*)(TS + OFF_SUB);
  int* i0p    = (int*)(TS + OFF_I0);
  int* order  = (int*)(TS + OFF_ORDER);
  int* tsv    = (int*)(TS + OFF_TSV);
  int* offs   = (int*)(TS + OFF_OFFS);
  int* runT   = (int*)(TS + OFF_RUNT);
  float* centsg = TS + OFF_CENTS;
  float* llp  = TS + OFF_LLP;
  float* Ls   = TS + OFF_LS;
  float* logu = TS + OFF_LOGU;
  float* PMb  = TS + OFF_PMB;
  float* PSb  = TS + OFF_PSB;
  float* PLm  = TS + OFF_PLM;
  float* PLs  = TS + OFF_PLS;

  hipLaunchKernelGGL(k_keys, dim3(1), dim3(64), 0, stream, sub, i0p);
  hipLaunchKernelGGL(k_gumbel, dim3((NPT + 255)/256, KC - 1), dim3(256), 0, stream,
                     sub, TS + OFF_Q);
  hipLaunchKernelGGL(k_gemm, dim3((NPT + 63)/64), dim3(256), 0, stream,
                     emb, W1, b1, TS + OFF_H);
  hipLaunchKernelGGL(k_cl, dim3((NPT + 3)/4), dim3(256), 0, stream,
                     TS + OFF_H, protos, TS + OFF_CL);
  hipLaunchKernelGGL(k_sort, dim3(1), dim3(512), 0, stream, jt, order, tsv, offs);
  hipLaunchKernelGGL(k_km, dim3(1), dim3(1024), 0, stream,
                     pos, i0p, TS + OFF_Q, centsg);

  for (int it = 0; it < 10; ++it)
    hipLaunchKernelGGL(k_lloyd, dim3(LGB), dim3(512), 0, stream,
                       pos, centsg, llp, (it == 0) ? 1 : 0);

  hipLaunchKernelGGL(k_cb, dim3(NBLK), dim3(512), 0, stream,
                     pos, TS + OFF_CL, order, tsv, centsg, llp, Ls, runT);

  hipLaunchKernelGGL(k_sink<1>, dim3(NBLK), dim3(512), 0, stream,
                     Ls, logu, offs, runT, tsv, PMb, PSb, PLm, PLs);
  for (int it = 1; it < SINK_IT; ++it)
    hipLaunchKernelGGL(k_sink<0>, dim3(NBLK), dim3(512), 0, stream,
                       Ls, logu, offs, runT, tsv, PMb, PSb, PLm, PLs);

  hipLaunchKernelGGL(k_fin, dim3(NBLK), dim3(512), 0, stream,
                     Ls, logu, offs, runT, tsv, order, PMb, PSb, vals);

  hipLaunchKernelGGL(k_T, dim3(NPT), dim3(256), 0, stream, vals, jt, T);
  hipLaunchKernelGGL(k_logits, dim3((NPT*KC + 255)/256), dim3(256), 0, stream, vals);
}